// Round 4
// baseline (266.358 us; speedup 1.0000x reference)
//
#include <hip/hip_runtime.h>

// Sizes (fixed by the problem)
#define BB 32
#define MM 128
#define PP 20
#define AA 32
#define TT 32
#define HH 32
#define EE 64

// ---------------------------------------------------------------------------
// Vectorized 64x64 matvec: out[c] = sum_i x[i] * W[i][c].
// Lane decomposition within a 64-lane wave: s = lane>>4, t = lane&15
// (4 channels 4t..4t+3). Returns fully-reduced float4 (valid in ALL lanes).
// W row-major [64][64]. xrow may be LDS or global.
// ---------------------------------------------------------------------------
__device__ __forceinline__ float4 matvec64(const float* __restrict__ W,
                                           const float* __restrict__ xrow,
                                           int s, int t)
{
    const float4* __restrict__ Wv = (const float4*)W;
    const float4* __restrict__ xv = (const float4*)xrow;
    float4 acc = make_float4(0.f, 0.f, 0.f, 0.f);
#pragma unroll
    for (int ii = 0; ii < 4; ++ii) {
        const float4 xx = xv[s * 4 + ii];
        const int ib = s * 16 + ii * 4;
        const float4 w0 = Wv[(ib + 0) * 16 + t];
        const float4 w1 = Wv[(ib + 1) * 16 + t];
        const float4 w2 = Wv[(ib + 2) * 16 + t];
        const float4 w3 = Wv[(ib + 3) * 16 + t];
        acc.x = fmaf(xx.x, w0.x, acc.x); acc.y = fmaf(xx.x, w0.y, acc.y);
        acc.z = fmaf(xx.x, w0.z, acc.z); acc.w = fmaf(xx.x, w0.w, acc.w);
        acc.x = fmaf(xx.y, w1.x, acc.x); acc.y = fmaf(xx.y, w1.y, acc.y);
        acc.z = fmaf(xx.y, w1.z, acc.z); acc.w = fmaf(xx.y, w1.w, acc.w);
        acc.x = fmaf(xx.z, w2.x, acc.x); acc.y = fmaf(xx.z, w2.y, acc.y);
        acc.z = fmaf(xx.z, w2.z, acc.z); acc.w = fmaf(xx.z, w2.w, acc.w);
        acc.x = fmaf(xx.w, w3.x, acc.x); acc.y = fmaf(xx.w, w3.y, acc.y);
        acc.z = fmaf(xx.w, w3.z, acc.z); acc.w = fmaf(xx.w, w3.w, acc.w);
    }
    acc.x += __shfl_xor(acc.x, 16); acc.y += __shfl_xor(acc.y, 16);
    acc.z += __shfl_xor(acc.z, 16); acc.w += __shfl_xor(acc.w, 16);
    acc.x += __shfl_xor(acc.x, 32); acc.y += __shfl_xor(acc.y, 32);
    acc.z += __shfl_xor(acc.z, 32); acc.w += __shfl_xor(acc.w, 32);
    return acc;
}

// ---------------------------------------------------------------------------
// Fused local-graph + QKV projection kernel. 128 threads (2 waves).
// Blocks [0, B*M): map group (b,m) -> map_emb row, Qb[b][m], Kb[b][m+1], Vb[b][m+1]
// Blocks [B*M, B*M+B): agent 0 of batch b -> target[b], Kb[b][0], Vb[b][0]
// Also zeroes the per-batch completion counters (blocks 0..31).
// Exact simplification: neighbor-max half == plain max half for P>=2, e>=0.
// ---------------------------------------------------------------------------
template <int IN>
__device__ __forceinline__ void lg_qkv_body(const float* __restrict__ xg, int P,
                                            const float* __restrict__ W1, const float* __restrict__ b1,
                                            const float* __restrict__ g1, const float* __restrict__ be1,
                                            const float* __restrict__ W2, const float* __restrict__ b2,
                                            const float* __restrict__ g2, const float* __restrict__ be2,
                                            float* __restrict__ embRow,
                                            const float* __restrict__ Wq, const float* __restrict__ bq,
                                            const float* __restrict__ Wk, const float* __restrict__ bk,
                                            const float* __restrict__ Wv, const float* __restrict__ bv,
                                            float* __restrict__ Qrow,
                                            float* __restrict__ Krow,
                                            float* __restrict__ Vrow)
{
    const int tid  = threadIdx.x;      // 0..127
    const int wave = tid >> 6;
    const int lane = tid & 63;
    const int sub  = tid >> 5;         // 0..3
    const int c    = tid & 31;

    __shared__ __align__(16) float aslot[4][32];
    __shared__ __align__(16) float wmax[2][32];
    __shared__ __align__(16) float xrow[EE];

    float w1c[IN];
#pragma unroll
    for (int k = 0; k < IN; ++k) w1c[k] = W1[k * HH + c];
    float w2c[HH];
#pragma unroll
    for (int k = 0; k < HH; ++k) w2c[k] = W2[k * HH + c];
    const float b1c = b1[c], g1c = g1[c], be1c = be1[c];
    const float b2c = b2[c], g2c = g2[c], be2c = be2[c];

    float cmax = -1e30f;

    for (int p0 = 0; p0 < P; p0 += 4) {
        const int p = p0 + sub;                // P divisible by 4 (20, 32)
        const float* xp = xg + (long)p * IN;

        float h = b1c;
        if (IN == 16) {
            const float4* xp4 = (const float4*)xp;
            const float4 x0 = xp4[0], x1 = xp4[1], x2 = xp4[2], x3 = xp4[3];
            h = fmaf(x0.x, w1c[0], h);  h = fmaf(x0.y, w1c[1], h);
            h = fmaf(x0.z, w1c[2], h);  h = fmaf(x0.w, w1c[3], h);
            h = fmaf(x1.x, w1c[4], h);  h = fmaf(x1.y, w1c[5], h);
            h = fmaf(x1.z, w1c[6], h);  h = fmaf(x1.w, w1c[7], h);
            h = fmaf(x2.x, w1c[8], h);  h = fmaf(x2.y, w1c[9], h);
            h = fmaf(x2.z, w1c[10], h); h = fmaf(x2.w, w1c[11], h);
            h = fmaf(x3.x, w1c[12], h); h = fmaf(x3.y, w1c[13], h);
            h = fmaf(x3.z, w1c[14], h); h = fmaf(x3.w, w1c[15], h);
        } else {
            const float4 x0 = *(const float4*)xp;
            h = fmaf(x0.x, w1c[0], h); h = fmaf(x0.y, w1c[1], h);
            h = fmaf(x0.z, w1c[2], h); h = fmaf(x0.w, w1c[3], h);
        }

        float sdot = h;
#pragma unroll
        for (int off = 16; off >= 1; off >>= 1) sdot += __shfl_xor(sdot, off, 32);
        const float mu = sdot * (1.0f / 32.0f);
        float d = h - mu;
        float sq = d * d;
#pragma unroll
        for (int off = 16; off >= 1; off >>= 1) sq += __shfl_xor(sq, off, 32);
        const float var = sq * (1.0f / 32.0f);
        float a = d * rsqrtf(var + 1e-5f) * g1c + be1c;
        a = fmaxf(a, 0.0f);

        // layer 2 via LDS broadcast (same-wave producer/consumer)
        aslot[sub][c] = a;
        const float4* av4 = (const float4*)aslot[sub];
        float h2 = b2c;
#pragma unroll
        for (int j = 0; j < 8; ++j) {
            const float4 aa = av4[j];
            h2 = fmaf(aa.x, w2c[4 * j + 0], h2);
            h2 = fmaf(aa.y, w2c[4 * j + 1], h2);
            h2 = fmaf(aa.z, w2c[4 * j + 2], h2);
            h2 = fmaf(aa.w, w2c[4 * j + 3], h2);
        }

        float s2 = h2;
#pragma unroll
        for (int off = 16; off >= 1; off >>= 1) s2 += __shfl_xor(s2, off, 32);
        const float mu2 = s2 * (1.0f / 32.0f);
        float d2 = h2 - mu2;
        float sq2 = d2 * d2;
#pragma unroll
        for (int off = 16; off >= 1; off >>= 1) sq2 += __shfl_xor(sq2, off, 32);
        const float var2 = sq2 * (1.0f / 32.0f);
        float e = d2 * rsqrtf(var2 + 1e-5f) * g2c + be2c;
        e = fmaxf(e, 0.0f);

        cmax = fmaxf(cmax, e);
    }

    cmax = fmaxf(cmax, __shfl_xor(cmax, 32));
    if (lane < 32) wmax[wave][lane] = cmax;
    __syncthreads();

    if (tid < 32) {
        const float fin = fmaxf(wmax[0][tid], wmax[1][tid]);
        xrow[tid]      = fin;
        xrow[tid + 32] = fin;
        embRow[tid]      = fin;
        embRow[tid + 32] = fin;
    }
    __syncthreads();

    const int s = lane >> 4, t = lane & 15;
    if (wave == 0) {
        if (Qrow) {
            float4 q4 = matvec64(Wq, xrow, s, t);
            if (s == 0) {
                const float4 bq4 = ((const float4*)bq)[t];
                float4 qo;
                qo.x = (q4.x + bq4.x) * 0.125f;
                qo.y = (q4.y + bq4.y) * 0.125f;
                qo.z = (q4.z + bq4.z) * 0.125f;
                qo.w = (q4.w + bq4.w) * 0.125f;
                ((float4*)Qrow)[t] = qo;
            }
        }
        float4 k4 = matvec64(Wk, xrow, s, t);
        if (s == 0) {
            const float4 kb4 = ((const float4*)bk)[t];
            float4 ko;
            ko.x = k4.x + kb4.x; ko.y = k4.y + kb4.y;
            ko.z = k4.z + kb4.z; ko.w = k4.w + kb4.w;
            ((float4*)Krow)[t] = ko;
        }
    } else {
        float4 v4 = matvec64(Wv, xrow, s, t);
        if (s == 0) {
            const float4 vb4 = ((const float4*)bv)[t];
            float4 vo;
            vo.x = v4.x + vb4.x; vo.y = v4.y + vb4.y;
            vo.z = v4.z + vb4.z; vo.w = v4.w + vb4.w;
            ((float4*)Vrow)[t] = vo;
        }
    }
}

__global__ void lg_qkv_kernel(const float* __restrict__ map_states,
                              const float* __restrict__ agent_states,
                              const float* __restrict__ mW1, const float* __restrict__ mb1,
                              const float* __restrict__ mg1, const float* __restrict__ mbe1,
                              const float* __restrict__ mW2, const float* __restrict__ mb2,
                              const float* __restrict__ mg2, const float* __restrict__ mbe2,
                              const float* __restrict__ aW1, const float* __restrict__ ab1,
                              const float* __restrict__ ag1, const float* __restrict__ abe1,
                              const float* __restrict__ aW2, const float* __restrict__ ab2,
                              const float* __restrict__ ag2, const float* __restrict__ abe2,
                              const float* __restrict__ Wq, const float* __restrict__ bq,
                              const float* __restrict__ Wk, const float* __restrict__ bk,
                              const float* __restrict__ Wv, const float* __restrict__ bv,
                              float* __restrict__ map_emb,
                              float* __restrict__ target,
                              float* __restrict__ Qb,
                              float* __restrict__ Kb,
                              float* __restrict__ Vb,
                              int* __restrict__ cnt)
{
    const int g = blockIdx.x;
    if (g < BB && threadIdx.x == 0) cnt[g] = 0;   // zero per-batch counters
    if (g < BB * MM) {
        const int b = g >> 7, m = g & 127;
        lg_qkv_body<16>(map_states + (long)g * PP * 16, PP,
                        mW1, mb1, mg1, mbe1, mW2, mb2, mg2, mbe2,
                        map_emb + (long)g * EE,
                        Wq, bq, Wk, bk, Wv, bv,
                        Qb + (long)g * EE,
                        Kb + ((long)b * 129 + 1 + m) * EE,
                        Vb + ((long)b * 129 + 1 + m) * EE);
    } else {
        const int b = g - BB * MM;
        lg_qkv_body<4>(agent_states + (long)b * AA * TT * 4, TT,
                       aW1, ab1, ag1, abe1, aW2, ab2, ag2, abe2,
                       target + (long)b * EE,
                       Wq, bq, Wk, bk, Wv, bv,
                       nullptr,
                       Kb + (long)b * 129 * EE,
                       Vb + (long)b * 129 * EE);
    }
}

// ---------------------------------------------------------------------------
// a2m attention + output proj + residual + fused K2/V2 projection; the LAST
// finishing block of each batch additionally computes the target row (t_a +
// t_m2a) for that batch — no separate kernel, no full-grid drain.
// One block (1 wave) per (b, query).
// ---------------------------------------------------------------------------
__global__ void attn_fused_kernel(const float* __restrict__ map_emb,
                                  const float* __restrict__ Qb,
                                  const float* __restrict__ Kb,
                                  const float* __restrict__ Vb,
                                  const float* __restrict__ target,
                                  const float* __restrict__ Wo, const float* __restrict__ bo,
                                  const float* __restrict__ Wk2, const float* __restrict__ bk2,
                                  const float* __restrict__ Wv2, const float* __restrict__ bv2,
                                  const float* __restrict__ Wq2, const float* __restrict__ bq2,
                                  const float* __restrict__ Wo2, const float* __restrict__ bo2,
                                  const float* __restrict__ Wv1, const float* __restrict__ bv1,
                                  const float* __restrict__ Wo1, const float* __restrict__ bo1,
                                  float* __restrict__ K2,   // [B,128,64]
                                  float* __restrict__ V2,   // [B,128,64]
                                  int*   __restrict__ cnt,  // [B]
                                  float* __restrict__ out)  // [B,129,64]
{
    const int blk  = blockIdx.x;
    const int b    = blk >> 7;
    const int q    = blk & 127;
    const int lane = threadIdx.x;
    const int s = lane >> 4, t = lane & 15;

    __shared__ __align__(16) float sc[132];
    __shared__ __align__(16) float av[EE];
    __shared__ __align__(16) float resrow[EE];
    __shared__ __align__(16) float tmp[EE];

    const float4 q4 = ((const float4*)(Qb + ((long)b * MM + q) * EE))[t];

    // ---- scores: 4 keys/iter (j = 4*it + s), coalesced float4 K reads ----
    const float* Kbase = Kb + (long)b * 129 * EE;
    float mx = -1e30f;
#pragma unroll 4
    for (int it = 0; it < 33; ++it) {
        const int j = it * 4 + s;
        const bool valid = (j < 129);
        float p = 0.0f;
        if (valid) {
            const float4 k4 = ((const float4*)(Kbase + (long)j * EE))[t];
            p = q4.x * k4.x + q4.y * k4.y + q4.z * k4.z + q4.w * k4.w;
        }
        p += __shfl_xor(p, 1); p += __shfl_xor(p, 2);
        p += __shfl_xor(p, 4); p += __shfl_xor(p, 8);
        if (valid) {
            mx = fmaxf(mx, p);
            if (t == 0) sc[j] = p;
        }
    }
#pragma unroll
    for (int off = 32; off >= 1; off >>= 1) mx = fmaxf(mx, __shfl_xor(mx, off));
    __syncthreads();

    float sum = 0.0f;
    for (int j = lane; j < 129; j += 64) {
        const float e = __expf(sc[j] - mx);
        sc[j] = e;
        sum += e;
    }
#pragma unroll
    for (int off = 32; off >= 1; off >>= 1) sum += __shfl_xor(sum, off);
    const float inv = 1.0f / sum;
    __syncthreads();

    // ---- PV: float4 V reads (j = 4*it + s), reduce across s ----
    const float* Vbase = Vb + (long)b * 129 * EE;
    float4 a4 = make_float4(0.f, 0.f, 0.f, 0.f);
#pragma unroll 4
    for (int it = 0; it < 33; ++it) {
        const int j = it * 4 + s;
        if (j < 129) {
            const float w = sc[j];
            const float4 v4 = ((const float4*)(Vbase + (long)j * EE))[t];
            a4.x = fmaf(w, v4.x, a4.x); a4.y = fmaf(w, v4.y, a4.y);
            a4.z = fmaf(w, v4.z, a4.z); a4.w = fmaf(w, v4.w, a4.w);
        }
    }
    a4.x += __shfl_xor(a4.x, 16); a4.y += __shfl_xor(a4.y, 16);
    a4.z += __shfl_xor(a4.z, 16); a4.w += __shfl_xor(a4.w, 16);
    a4.x += __shfl_xor(a4.x, 32); a4.y += __shfl_xor(a4.y, 32);
    a4.z += __shfl_xor(a4.z, 32); a4.w += __shfl_xor(a4.w, 32);
    if (s == 0) {
        float4 o; o.x = a4.x * inv; o.y = a4.y * inv; o.z = a4.z * inv; o.w = a4.w * inv;
        ((float4*)av)[t] = o;
    }
    __syncthreads();

    // ---- output projection + residual ----
    const float4 o4 = matvec64(Wo, av, s, t);
    const float4 bo4 = ((const float4*)bo)[t];
    const float4 x4 = ((const float4*)(map_emb + ((long)b * MM + q) * EE))[t];
    float4 res;
    res.x = o4.x + bo4.x + x4.x;
    res.y = o4.y + bo4.y + x4.y;
    res.z = o4.z + bo4.z + x4.z;
    res.w = o4.w + bo4.w + x4.w;
    if (s == 0) {
        ((float4*)(out + ((long)b * 129 + 1 + q) * EE))[t] = res;
        ((float4*)resrow)[t] = res;
    }
    __syncthreads();

    // ---- fused K2/V2 projection of the result row ----
    const float4 k4 = matvec64(Wk2, resrow, s, t);
    const float4 v4 = matvec64(Wv2, resrow, s, t);
    if (s == 0) {
        const float4 kb4 = ((const float4*)bk2)[t];
        const float4 vb4 = ((const float4*)bv2)[t];
        float4 ko, vo;
        ko.x = k4.x + kb4.x; ko.y = k4.y + kb4.y; ko.z = k4.z + kb4.z; ko.w = k4.w + kb4.w;
        vo.x = v4.x + vb4.x; vo.y = v4.y + vb4.y; vo.z = v4.z + vb4.z; vo.w = v4.w + vb4.w;
        ((float4*)(K2 + ((long)b * MM + q) * EE))[t] = ko;
        ((float4*)(V2 + ((long)b * MM + q) * EE))[t] = vo;
    }

    // ---- last block of this batch computes the target row ----
    __threadfence();                        // release K2/V2 writes (device scope)
    int old = 0;
    if (lane == 0) old = atomicAdd(&cnt[b], 1);
    old = __shfl(old, 0);
    if (old != MM - 1) return;
    __threadfence();                        // acquire other blocks' K2/V2

    // reuse LDS: resrow -> trow
    float* trow = resrow;
    trow[lane] = target[(long)b * EE + lane];
    __syncthreads();

    // t_a = (t @ Wv1 + bv1) @ Wo1 + bo1   (softmax over one key == 1)
    const float4 v1 = matvec64(Wv1, trow, s, t);
    if (s == 0) {
        const float4 bv4 = ((const float4*)bv1)[t];
        float4 w; w.x = v1.x + bv4.x; w.y = v1.y + bv4.y; w.z = v1.z + bv4.z; w.w = v1.w + bv4.w;
        ((float4*)tmp)[t] = w;
    }
    __syncthreads();
    float4 ta = matvec64(Wo1, tmp, s, t);
    {
        const float4 bo14 = ((const float4*)bo1)[t];
        ta.x += bo14.x; ta.y += bo14.y; ta.z += bo14.z; ta.w += bo14.w;
    }

    // t_m2a query (pre-scaled)
    float4 qt = matvec64(Wq2, trow, s, t);
    {
        const float4 bq4 = ((const float4*)bq2)[t];
        qt.x = (qt.x + bq4.x) * 0.125f;
        qt.y = (qt.y + bq4.y) * 0.125f;
        qt.z = (qt.z + bq4.z) * 0.125f;
        qt.w = (qt.w + bq4.w) * 0.125f;
    }

    const float* K2base = K2 + (long)b * MM * EE;
    float mx2 = -1e30f;
#pragma unroll 4
    for (int it = 0; it < 32; ++it) {
        const int j = it * 4 + s;
        const float4 kk = ((const float4*)(K2base + (long)j * EE))[t];
        float p = qt.x * kk.x + qt.y * kk.y + qt.z * kk.z + qt.w * kk.w;
        p += __shfl_xor(p, 1); p += __shfl_xor(p, 2);
        p += __shfl_xor(p, 4); p += __shfl_xor(p, 8);
        mx2 = fmaxf(mx2, p);
        if (t == 0) sc[j] = p;
    }
#pragma unroll
    for (int off = 32; off >= 1; off >>= 1) mx2 = fmaxf(mx2, __shfl_xor(mx2, off));
    __syncthreads();

    float sum2 = 0.0f;
#pragma unroll
    for (int j = lane; j < MM; j += 64) {
        const float e = __expf(sc[j] - mx2);
        sc[j] = e;
        sum2 += e;
    }
#pragma unroll
    for (int off = 32; off >= 1; off >>= 1) sum2 += __shfl_xor(sum2, off);
    const float inv2 = 1.0f / sum2;
    __syncthreads();

    const float* V2base = V2 + (long)b * MM * EE;
    float4 b4 = make_float4(0.f, 0.f, 0.f, 0.f);
#pragma unroll 4
    for (int it = 0; it < 32; ++it) {
        const int j = it * 4 + s;
        const float w = sc[j];
        const float4 vv = ((const float4*)(V2base + (long)j * EE))[t];
        b4.x = fmaf(w, vv.x, b4.x); b4.y = fmaf(w, vv.y, b4.y);
        b4.z = fmaf(w, vv.z, b4.z); b4.w = fmaf(w, vv.w, b4.w);
    }
    b4.x += __shfl_xor(b4.x, 16); b4.y += __shfl_xor(b4.y, 16);
    b4.z += __shfl_xor(b4.z, 16); b4.w += __shfl_xor(b4.w, 16);
    b4.x += __shfl_xor(b4.x, 32); b4.y += __shfl_xor(b4.y, 32);
    b4.z += __shfl_xor(b4.z, 32); b4.w += __shfl_xor(b4.w, 32);
    if (s == 0) {
        float4 o; o.x = b4.x * inv2; o.y = b4.y * inv2; o.z = b4.z * inv2; o.w = b4.w * inv2;
        ((float4*)av)[t] = o;
    }
    __syncthreads();

    const float4 ot = matvec64(Wo2, av, s, t);
    if (s == 0) {
        const float4 bo24 = ((const float4*)bo2)[t];
        float4 r;
        r.x = ta.x + ot.x + bo24.x;
        r.y = ta.y + ot.y + bo24.y;
        r.z = ta.z + ot.z + bo24.z;
        r.w = ta.w + ot.w + bo24.w;
        ((float4*)(out + (long)b * 129 * EE))[t] = r;
    }
}

// ---------------------------------------------------------------------------
extern "C" void kernel_launch(void* const* d_in, const int* in_sizes, int n_in,
                              void* d_out, int out_size, void* d_ws, size_t ws_size,
                              hipStream_t stream)
{
    const float* map_states   = (const float*)d_in[0];
    const float* agent_states = (const float*)d_in[1];
    const float* m_W1 = (const float*)d_in[2];
    const float* m_b1 = (const float*)d_in[3];
    const float* m_g1 = (const float*)d_in[4];
    const float* m_be1 = (const float*)d_in[5];
    const float* m_W2 = (const float*)d_in[6];
    const float* m_b2 = (const float*)d_in[7];
    const float* m_g2 = (const float*)d_in[8];
    const float* m_be2 = (const float*)d_in[9];
    const float* a_W1 = (const float*)d_in[10];
    const float* a_b1 = (const float*)d_in[11];
    const float* a_g1 = (const float*)d_in[12];
    const float* a_be1 = (const float*)d_in[13];
    const float* a_W2 = (const float*)d_in[14];
    const float* a_b2 = (const float*)d_in[15];
    const float* a_g2 = (const float*)d_in[16];
    const float* a_be2 = (const float*)d_in[17];
    const float* att_Wq = (const float*)d_in[18];
    const float* att_bq = (const float*)d_in[19];
    const float* att_Wk = (const float*)d_in[20];
    const float* att_bk = (const float*)d_in[21];
    const float* att_Wv = (const float*)d_in[22];
    const float* att_bv = (const float*)d_in[23];
    const float* att_Wo = (const float*)d_in[24];
    const float* att_bo = (const float*)d_in[25];

    float* out = (float*)d_out;

    // ws layout (floats)
    float* ws      = (float*)d_ws;
    float* map_emb = ws;                          // 32*128*64
    float* target  = map_emb + BB * MM * EE;      // 32*64
    float* Qb      = target + BB * EE;            // 32*128*64
    float* Kb      = Qb + BB * MM * EE;           // 32*129*64
    float* Vb      = Kb + BB * 129 * EE;          // 32*129*64
    float* K2      = Vb + BB * 129 * EE;          // 32*128*64
    float* V2      = K2 + BB * MM * EE;           // 32*128*64
    int*   cnt     = (int*)(V2 + BB * MM * EE);   // 32 ints

    const float* Wq0 = att_Wq + 0 * EE * EE; const float* bq0 = att_bq + 0 * EE;
    const float* Wk0 = att_Wk + 0 * EE * EE; const float* bk0 = att_bk + 0 * EE;
    const float* Wv0 = att_Wv + 0 * EE * EE; const float* bv0 = att_bv + 0 * EE;
    const float* Wo0 = att_Wo + 0 * EE * EE; const float* bo0 = att_bo + 0 * EE;
    const float* Wv1 = att_Wv + 1 * EE * EE; const float* bv1 = att_bv + 1 * EE;
    const float* Wo1 = att_Wo + 1 * EE * EE; const float* bo1 = att_bo + 1 * EE;
    const float* Wq2 = att_Wq + 2 * EE * EE; const float* bq2 = att_bq + 2 * EE;
    const float* Wk2 = att_Wk + 2 * EE * EE; const float* bk2 = att_bk + 2 * EE;
    const float* Wv2 = att_Wv + 2 * EE * EE; const float* bv2 = att_bv + 2 * EE;
    const float* Wo2 = att_Wo + 2 * EE * EE; const float* bo2 = att_bo + 2 * EE;

    // 1. fused local graphs + QKV projections (+ counter zeroing)
    hipLaunchKernelGGL(lg_qkv_kernel, dim3(BB * MM + BB), dim3(128), 0, stream,
                       map_states, agent_states,
                       m_W1, m_b1, m_g1, m_be1, m_W2, m_b2, m_g2, m_be2,
                       a_W1, a_b1, a_g1, a_be1, a_W2, a_b2, a_g2, a_be2,
                       Wq0, bq0, Wk0, bk0, Wv0, bv0,
                       map_emb, target, Qb, Kb, Vb, cnt);

    // 2. a2m attention + residual + K2/V2 + per-batch target (last block)
    hipLaunchKernelGGL(attn_fused_kernel, dim3(BB * MM), dim3(64), 0, stream,
                       map_emb, Qb, Kb, Vb, target, Wo0, bo0,
                       Wk2, bk2, Wv2, bv2, Wq2, bq2, Wo2, bo2,
                       Wv1, bv1, Wo1, bo1, K2, V2, cnt, out);
}

// Round 5
// 185.178 us; speedup vs baseline: 1.4384x; 1.4384x over previous
//
#include <hip/hip_runtime.h>

// Sizes (fixed by the problem)
#define BB 32
#define MM 128
#define PP 20
#define AA 32
#define TT 32
#define HH 32
#define EE 64

// ---------------------------------------------------------------------------
// Vectorized 64x64 matvec: out[c] = sum_i x[i] * W[i][c].
// Lane decomposition within a 64-lane wave: s = lane>>4, t = lane&15
// (4 channels 4t..4t+3). Returns fully-reduced float4 (valid in ALL lanes).
// W row-major [64][64]. xrow may be LDS or global.
// ---------------------------------------------------------------------------
__device__ __forceinline__ float4 matvec64(const float* __restrict__ W,
                                           const float* __restrict__ xrow,
                                           int s, int t)
{
    const float4* __restrict__ Wv = (const float4*)W;
    const float4* __restrict__ xv = (const float4*)xrow;
    float4 acc = make_float4(0.f, 0.f, 0.f, 0.f);
#pragma unroll
    for (int ii = 0; ii < 4; ++ii) {
        const float4 xx = xv[s * 4 + ii];
        const int ib = s * 16 + ii * 4;
        const float4 w0 = Wv[(ib + 0) * 16 + t];
        const float4 w1 = Wv[(ib + 1) * 16 + t];
        const float4 w2 = Wv[(ib + 2) * 16 + t];
        const float4 w3 = Wv[(ib + 3) * 16 + t];
        acc.x = fmaf(xx.x, w0.x, acc.x); acc.y = fmaf(xx.x, w0.y, acc.y);
        acc.z = fmaf(xx.x, w0.z, acc.z); acc.w = fmaf(xx.x, w0.w, acc.w);
        acc.x = fmaf(xx.y, w1.x, acc.x); acc.y = fmaf(xx.y, w1.y, acc.y);
        acc.z = fmaf(xx.y, w1.z, acc.z); acc.w = fmaf(xx.y, w1.w, acc.w);
        acc.x = fmaf(xx.z, w2.x, acc.x); acc.y = fmaf(xx.z, w2.y, acc.y);
        acc.z = fmaf(xx.z, w2.z, acc.z); acc.w = fmaf(xx.z, w2.w, acc.w);
        acc.x = fmaf(xx.w, w3.x, acc.x); acc.y = fmaf(xx.w, w3.y, acc.y);
        acc.z = fmaf(xx.w, w3.z, acc.z); acc.w = fmaf(xx.w, w3.w, acc.w);
    }
    acc.x += __shfl_xor(acc.x, 16); acc.y += __shfl_xor(acc.y, 16);
    acc.z += __shfl_xor(acc.z, 16); acc.w += __shfl_xor(acc.w, 16);
    acc.x += __shfl_xor(acc.x, 32); acc.y += __shfl_xor(acc.y, 32);
    acc.z += __shfl_xor(acc.z, 32); acc.w += __shfl_xor(acc.w, 32);
    return acc;
}

// ---------------------------------------------------------------------------
// Fused local-graph + QKV projection kernel. 128 threads (2 waves).
// Blocks [0, B*M): map group (b,m) -> map_emb row, Qb[b][m], Kb[b][m+1], Vb[b][m+1]
// Blocks [B*M, B*M+B): agent 0 of batch b -> target[b], Kb[b][0], Vb[b][0]
// Exact simplification: neighbor-max half == plain max half for P>=2, e>=0.
// ---------------------------------------------------------------------------
template <int IN>
__device__ __forceinline__ void lg_qkv_body(const float* __restrict__ xg, int P,
                                            const float* __restrict__ W1, const float* __restrict__ b1,
                                            const float* __restrict__ g1, const float* __restrict__ be1,
                                            const float* __restrict__ W2, const float* __restrict__ b2,
                                            const float* __restrict__ g2, const float* __restrict__ be2,
                                            float* __restrict__ embRow,
                                            const float* __restrict__ Wq, const float* __restrict__ bq,
                                            const float* __restrict__ Wk, const float* __restrict__ bk,
                                            const float* __restrict__ Wv, const float* __restrict__ bv,
                                            float* __restrict__ Qrow,
                                            float* __restrict__ Krow,
                                            float* __restrict__ Vrow)
{
    const int tid  = threadIdx.x;      // 0..127
    const int wave = tid >> 6;
    const int lane = tid & 63;
    const int sub  = tid >> 5;         // 0..3
    const int c    = tid & 31;

    __shared__ __align__(16) float aslot[4][32];
    __shared__ __align__(16) float wmax[2][32];
    __shared__ __align__(16) float xrow[EE];

    float w1c[IN];
#pragma unroll
    for (int k = 0; k < IN; ++k) w1c[k] = W1[k * HH + c];
    float w2c[HH];
#pragma unroll
    for (int k = 0; k < HH; ++k) w2c[k] = W2[k * HH + c];
    const float b1c = b1[c], g1c = g1[c], be1c = be1[c];
    const float b2c = b2[c], g2c = g2[c], be2c = be2[c];

    float cmax = -1e30f;

    for (int p0 = 0; p0 < P; p0 += 4) {
        const int p = p0 + sub;                // P divisible by 4 (20, 32)
        const float* xp = xg + (long)p * IN;

        float h = b1c;
        if (IN == 16) {
            const float4* xp4 = (const float4*)xp;
            const float4 x0 = xp4[0], x1 = xp4[1], x2 = xp4[2], x3 = xp4[3];
            h = fmaf(x0.x, w1c[0], h);  h = fmaf(x0.y, w1c[1], h);
            h = fmaf(x0.z, w1c[2], h);  h = fmaf(x0.w, w1c[3], h);
            h = fmaf(x1.x, w1c[4], h);  h = fmaf(x1.y, w1c[5], h);
            h = fmaf(x1.z, w1c[6], h);  h = fmaf(x1.w, w1c[7], h);
            h = fmaf(x2.x, w1c[8], h);  h = fmaf(x2.y, w1c[9], h);
            h = fmaf(x2.z, w1c[10], h); h = fmaf(x2.w, w1c[11], h);
            h = fmaf(x3.x, w1c[12], h); h = fmaf(x3.y, w1c[13], h);
            h = fmaf(x3.z, w1c[14], h); h = fmaf(x3.w, w1c[15], h);
        } else {
            const float4 x0 = *(const float4*)xp;
            h = fmaf(x0.x, w1c[0], h); h = fmaf(x0.y, w1c[1], h);
            h = fmaf(x0.z, w1c[2], h); h = fmaf(x0.w, w1c[3], h);
        }

        float sdot = h;
#pragma unroll
        for (int off = 16; off >= 1; off >>= 1) sdot += __shfl_xor(sdot, off, 32);
        const float mu = sdot * (1.0f / 32.0f);
        float d = h - mu;
        float sq = d * d;
#pragma unroll
        for (int off = 16; off >= 1; off >>= 1) sq += __shfl_xor(sq, off, 32);
        const float var = sq * (1.0f / 32.0f);
        float a = d * rsqrtf(var + 1e-5f) * g1c + be1c;
        a = fmaxf(a, 0.0f);

        // layer 2 via LDS broadcast (same-wave producer/consumer)
        aslot[sub][c] = a;
        const float4* av4 = (const float4*)aslot[sub];
        float h2 = b2c;
#pragma unroll
        for (int j = 0; j < 8; ++j) {
            const float4 aa = av4[j];
            h2 = fmaf(aa.x, w2c[4 * j + 0], h2);
            h2 = fmaf(aa.y, w2c[4 * j + 1], h2);
            h2 = fmaf(aa.z, w2c[4 * j + 2], h2);
            h2 = fmaf(aa.w, w2c[4 * j + 3], h2);
        }

        float s2 = h2;
#pragma unroll
        for (int off = 16; off >= 1; off >>= 1) s2 += __shfl_xor(s2, off, 32);
        const float mu2 = s2 * (1.0f / 32.0f);
        float d2 = h2 - mu2;
        float sq2 = d2 * d2;
#pragma unroll
        for (int off = 16; off >= 1; off >>= 1) sq2 += __shfl_xor(sq2, off, 32);
        const float var2 = sq2 * (1.0f / 32.0f);
        float e = d2 * rsqrtf(var2 + 1e-5f) * g2c + be2c;
        e = fmaxf(e, 0.0f);

        cmax = fmaxf(cmax, e);
    }

    cmax = fmaxf(cmax, __shfl_xor(cmax, 32));
    if (lane < 32) wmax[wave][lane] = cmax;
    __syncthreads();

    if (tid < 32) {
        const float fin = fmaxf(wmax[0][tid], wmax[1][tid]);
        xrow[tid]      = fin;
        xrow[tid + 32] = fin;
        embRow[tid]      = fin;
        embRow[tid + 32] = fin;
    }
    __syncthreads();

    const int s = lane >> 4, t = lane & 15;
    if (wave == 0) {
        if (Qrow) {
            float4 q4 = matvec64(Wq, xrow, s, t);
            if (s == 0) {
                const float4 bq4 = ((const float4*)bq)[t];
                float4 qo;
                qo.x = (q4.x + bq4.x) * 0.125f;
                qo.y = (q4.y + bq4.y) * 0.125f;
                qo.z = (q4.z + bq4.z) * 0.125f;
                qo.w = (q4.w + bq4.w) * 0.125f;
                ((float4*)Qrow)[t] = qo;
            }
        }
        float4 k4 = matvec64(Wk, xrow, s, t);
        if (s == 0) {
            const float4 kb4 = ((const float4*)bk)[t];
            float4 ko;
            ko.x = k4.x + kb4.x; ko.y = k4.y + kb4.y;
            ko.z = k4.z + kb4.z; ko.w = k4.w + kb4.w;
            ((float4*)Krow)[t] = ko;
        }
    } else {
        float4 v4 = matvec64(Wv, xrow, s, t);
        if (s == 0) {
            const float4 vb4 = ((const float4*)bv)[t];
            float4 vo;
            vo.x = v4.x + vb4.x; vo.y = v4.y + vb4.y;
            vo.z = v4.z + vb4.z; vo.w = v4.w + vb4.w;
            ((float4*)Vrow)[t] = vo;
        }
    }
}

__global__ void lg_qkv_kernel(const float* __restrict__ map_states,
                              const float* __restrict__ agent_states,
                              const float* __restrict__ mW1, const float* __restrict__ mb1,
                              const float* __restrict__ mg1, const float* __restrict__ mbe1,
                              const float* __restrict__ mW2, const float* __restrict__ mb2,
                              const float* __restrict__ mg2, const float* __restrict__ mbe2,
                              const float* __restrict__ aW1, const float* __restrict__ ab1,
                              const float* __restrict__ ag1, const float* __restrict__ abe1,
                              const float* __restrict__ aW2, const float* __restrict__ ab2,
                              const float* __restrict__ ag2, const float* __restrict__ abe2,
                              const float* __restrict__ Wq, const float* __restrict__ bq,
                              const float* __restrict__ Wk, const float* __restrict__ bk,
                              const float* __restrict__ Wv, const float* __restrict__ bv,
                              float* __restrict__ map_emb,
                              float* __restrict__ target,
                              float* __restrict__ Qb,
                              float* __restrict__ Kb,
                              float* __restrict__ Vb)
{
    const int g = blockIdx.x;
    if (g < BB * MM) {
        const int b = g >> 7, m = g & 127;
        lg_qkv_body<16>(map_states + (long)g * PP * 16, PP,
                        mW1, mb1, mg1, mbe1, mW2, mb2, mg2, mbe2,
                        map_emb + (long)g * EE,
                        Wq, bq, Wk, bk, Wv, bv,
                        Qb + (long)g * EE,
                        Kb + ((long)b * 129 + 1 + m) * EE,
                        Vb + ((long)b * 129 + 1 + m) * EE);
    } else {
        const int b = g - BB * MM;
        lg_qkv_body<4>(agent_states + (long)b * AA * TT * 4, TT,
                       aW1, ab1, ag1, abe1, aW2, ab2, ag2, abe2,
                       target + (long)b * EE,
                       Wq, bq, Wk, bk, Wv, bv,
                       nullptr,
                       Kb + (long)b * 129 * EE,
                       Vb + (long)b * 129 * EE);
    }
}

// ---------------------------------------------------------------------------
// a2m attention: loads precomputed Q, scores (coalesced float4 K), softmax,
// PV (coalesced float4 V + shfl reduce), output proj + residual -> d_out rows
// 1..128, fused K2/V2 projection of the result row.
// One block (1 wave) per (b, query). NO cross-block sync (fences cost more
// than a kernel boundary — measured R4: +82 µs from per-block __threadfence).
// ---------------------------------------------------------------------------
__global__ void attn_fused_kernel(const float* __restrict__ map_emb,
                                  const float* __restrict__ Qb,
                                  const float* __restrict__ Kb,
                                  const float* __restrict__ Vb,
                                  const float* __restrict__ Wo, const float* __restrict__ bo,
                                  const float* __restrict__ Wk2, const float* __restrict__ bk2,
                                  const float* __restrict__ Wv2, const float* __restrict__ bv2,
                                  float* __restrict__ K2,   // [B,128,64]
                                  float* __restrict__ V2,   // [B,128,64]
                                  float* __restrict__ out)  // [B,129,64]
{
    const int blk  = blockIdx.x;
    const int b    = blk >> 7;
    const int q    = blk & 127;
    const int lane = threadIdx.x;
    const int s = lane >> 4, t = lane & 15;

    __shared__ __align__(16) float sc[132];
    __shared__ __align__(16) float av[EE];
    __shared__ __align__(16) float resrow[EE];

    const float4 q4 = ((const float4*)(Qb + ((long)b * MM + q) * EE))[t];

    // ---- scores: 4 keys/iter (j = 4*it + s), coalesced float4 K reads ----
    const float* Kbase = Kb + (long)b * 129 * EE;
    float mx = -1e30f;
#pragma unroll 4
    for (int it = 0; it < 33; ++it) {
        const int j = it * 4 + s;
        const bool valid = (j < 129);
        float p = 0.0f;
        if (valid) {
            const float4 k4 = ((const float4*)(Kbase + (long)j * EE))[t];
            p = q4.x * k4.x + q4.y * k4.y + q4.z * k4.z + q4.w * k4.w;
        }
        p += __shfl_xor(p, 1); p += __shfl_xor(p, 2);
        p += __shfl_xor(p, 4); p += __shfl_xor(p, 8);
        if (valid) {
            mx = fmaxf(mx, p);
            if (t == 0) sc[j] = p;
        }
    }
#pragma unroll
    for (int off = 32; off >= 1; off >>= 1) mx = fmaxf(mx, __shfl_xor(mx, off));
    __syncthreads();

    float sum = 0.0f;
    for (int j = lane; j < 129; j += 64) {
        const float e = __expf(sc[j] - mx);
        sc[j] = e;
        sum += e;
    }
#pragma unroll
    for (int off = 32; off >= 1; off >>= 1) sum += __shfl_xor(sum, off);
    const float inv = 1.0f / sum;
    __syncthreads();

    // ---- PV: float4 V reads (j = 4*it + s), reduce across s ----
    const float* Vbase = Vb + (long)b * 129 * EE;
    float4 a4 = make_float4(0.f, 0.f, 0.f, 0.f);
#pragma unroll 4
    for (int it = 0; it < 33; ++it) {
        const int j = it * 4 + s;
        if (j < 129) {
            const float w = sc[j];
            const float4 v4 = ((const float4*)(Vbase + (long)j * EE))[t];
            a4.x = fmaf(w, v4.x, a4.x); a4.y = fmaf(w, v4.y, a4.y);
            a4.z = fmaf(w, v4.z, a4.z); a4.w = fmaf(w, v4.w, a4.w);
        }
    }
    a4.x += __shfl_xor(a4.x, 16); a4.y += __shfl_xor(a4.y, 16);
    a4.z += __shfl_xor(a4.z, 16); a4.w += __shfl_xor(a4.w, 16);
    a4.x += __shfl_xor(a4.x, 32); a4.y += __shfl_xor(a4.y, 32);
    a4.z += __shfl_xor(a4.z, 32); a4.w += __shfl_xor(a4.w, 32);
    if (s == 0) {
        float4 o; o.x = a4.x * inv; o.y = a4.y * inv; o.z = a4.z * inv; o.w = a4.w * inv;
        ((float4*)av)[t] = o;
    }
    __syncthreads();

    // ---- output projection + residual ----
    const float4 o4 = matvec64(Wo, av, s, t);
    const float4 bo4 = ((const float4*)bo)[t];
    const float4 x4 = ((const float4*)(map_emb + ((long)b * MM + q) * EE))[t];
    float4 res;
    res.x = o4.x + bo4.x + x4.x;
    res.y = o4.y + bo4.y + x4.y;
    res.z = o4.z + bo4.z + x4.z;
    res.w = o4.w + bo4.w + x4.w;
    if (s == 0) {
        ((float4*)(out + ((long)b * 129 + 1 + q) * EE))[t] = res;
        ((float4*)resrow)[t] = res;
    }
    __syncthreads();

    // ---- fused K2/V2 projection of the result row ----
    const float4 k4 = matvec64(Wk2, resrow, s, t);
    const float4 v4 = matvec64(Wv2, resrow, s, t);
    if (s == 0) {
        const float4 kb4 = ((const float4*)bk2)[t];
        const float4 vb4 = ((const float4*)bv2)[t];
        float4 ko, vo;
        ko.x = k4.x + kb4.x; ko.y = k4.y + kb4.y; ko.z = k4.z + kb4.z; ko.w = k4.w + kb4.w;
        vo.x = v4.x + vb4.x; vo.y = v4.y + vb4.y; vo.z = v4.z + vb4.z; vo.w = v4.w + vb4.w;
        ((float4*)(K2 + ((long)b * MM + q) * EE))[t] = ko;
        ((float4*)(V2 + ((long)b * MM + q) * EE))[t] = vo;
    }
}

// ---------------------------------------------------------------------------
// Target row: t_a (exact single-token shortcut) + t_m2a attention over 128
// map tokens. One block (1 wave) per batch. Writes d_out row 0.
// ---------------------------------------------------------------------------
__global__ void target_kernel(const float* __restrict__ target,
                              const float* __restrict__ K2, const float* __restrict__ V2,
                              const float* __restrict__ Wq2, const float* __restrict__ bq2,
                              const float* __restrict__ Wo2, const float* __restrict__ bo2,
                              const float* __restrict__ Wv1, const float* __restrict__ bv1,
                              const float* __restrict__ Wo1, const float* __restrict__ bo1,
                              float* __restrict__ out)
{
    const int b    = blockIdx.x;
    const int lane = threadIdx.x;
    const int s = lane >> 4, t = lane & 15;

    __shared__ __align__(16) float trow[EE];
    __shared__ __align__(16) float tmp[EE];
    __shared__ __align__(16) float sc[128];
    __shared__ __align__(16) float av[EE];

    trow[lane] = target[(long)b * EE + lane];
    __syncthreads();

    // t_a = (t @ Wv1 + bv1) @ Wo1 + bo1  (softmax over one key == 1)
    const float4 v1 = matvec64(Wv1, trow, s, t);
    if (s == 0) {
        const float4 bv4 = ((const float4*)bv1)[t];
        float4 w; w.x = v1.x + bv4.x; w.y = v1.y + bv4.y; w.z = v1.z + bv4.z; w.w = v1.w + bv4.w;
        ((float4*)tmp)[t] = w;
    }
    __syncthreads();
    float4 ta = matvec64(Wo1, tmp, s, t);
    {
        const float4 bo4 = ((const float4*)bo1)[t];
        ta.x += bo4.x; ta.y += bo4.y; ta.z += bo4.z; ta.w += bo4.w;
    }

    // t_m2a query (pre-scaled)
    float4 q4 = matvec64(Wq2, trow, s, t);
    {
        const float4 bq4 = ((const float4*)bq2)[t];
        q4.x = (q4.x + bq4.x) * 0.125f;
        q4.y = (q4.y + bq4.y) * 0.125f;
        q4.z = (q4.z + bq4.z) * 0.125f;
        q4.w = (q4.w + bq4.w) * 0.125f;
    }

    const float* Kbase = K2 + (long)b * MM * EE;
    float mx = -1e30f;
#pragma unroll 4
    for (int it = 0; it < 32; ++it) {
        const int j = it * 4 + s;
        const float4 k4 = ((const float4*)(Kbase + (long)j * EE))[t];
        float p = q4.x * k4.x + q4.y * k4.y + q4.z * k4.z + q4.w * k4.w;
        p += __shfl_xor(p, 1); p += __shfl_xor(p, 2);
        p += __shfl_xor(p, 4); p += __shfl_xor(p, 8);
        mx = fmaxf(mx, p);
        if (t == 0) sc[j] = p;
    }
#pragma unroll
    for (int off = 32; off >= 1; off >>= 1) mx = fmaxf(mx, __shfl_xor(mx, off));
    __syncthreads();

    float sum = 0.0f;
#pragma unroll
    for (int j = lane; j < MM; j += 64) {
        const float e = __expf(sc[j] - mx);
        sc[j] = e;
        sum += e;
    }
#pragma unroll
    for (int off = 32; off >= 1; off >>= 1) sum += __shfl_xor(sum, off);
    const float inv = 1.0f / sum;
    __syncthreads();

    // PV: float4 V reads, reduce across s
    const float* Vbase = V2 + (long)b * MM * EE;
    float4 b4 = make_float4(0.f, 0.f, 0.f, 0.f);
#pragma unroll 4
    for (int it = 0; it < 32; ++it) {
        const int j = it * 4 + s;
        const float w = sc[j];
        const float4 vv = ((const float4*)(Vbase + (long)j * EE))[t];
        b4.x = fmaf(w, vv.x, b4.x); b4.y = fmaf(w, vv.y, b4.y);
        b4.z = fmaf(w, vv.z, b4.z); b4.w = fmaf(w, vv.w, b4.w);
    }
    b4.x += __shfl_xor(b4.x, 16); b4.y += __shfl_xor(b4.y, 16);
    b4.z += __shfl_xor(b4.z, 16); b4.w += __shfl_xor(b4.w, 16);
    b4.x += __shfl_xor(b4.x, 32); b4.y += __shfl_xor(b4.y, 32);
    b4.z += __shfl_xor(b4.z, 32); b4.w += __shfl_xor(b4.w, 32);
    if (s == 0) {
        float4 o; o.x = b4.x * inv; o.y = b4.y * inv; o.z = b4.z * inv; o.w = b4.w * inv;
        ((float4*)av)[t] = o;
    }
    __syncthreads();

    const float4 o4 = matvec64(Wo2, av, s, t);
    if (s == 0) {
        const float4 bo4 = ((const float4*)bo2)[t];
        float4 r;
        r.x = ta.x + o4.x + bo4.x;
        r.y = ta.y + o4.y + bo4.y;
        r.z = ta.z + o4.z + bo4.z;
        r.w = ta.w + o4.w + bo4.w;
        ((float4*)(out + (long)b * 129 * EE))[t] = r;
    }
}

// ---------------------------------------------------------------------------
extern "C" void kernel_launch(void* const* d_in, const int* in_sizes, int n_in,
                              void* d_out, int out_size, void* d_ws, size_t ws_size,
                              hipStream_t stream)
{
    const float* map_states   = (const float*)d_in[0];
    const float* agent_states = (const float*)d_in[1];
    const float* m_W1 = (const float*)d_in[2];
    const float* m_b1 = (const float*)d_in[3];
    const float* m_g1 = (const float*)d_in[4];
    const float* m_be1 = (const float*)d_in[5];
    const float* m_W2 = (const float*)d_in[6];
    const float* m_b2 = (const float*)d_in[7];
    const float* m_g2 = (const float*)d_in[8];
    const float* m_be2 = (const float*)d_in[9];
    const float* a_W1 = (const float*)d_in[10];
    const float* a_b1 = (const float*)d_in[11];
    const float* a_g1 = (const float*)d_in[12];
    const float* a_be1 = (const float*)d_in[13];
    const float* a_W2 = (const float*)d_in[14];
    const float* a_b2 = (const float*)d_in[15];
    const float* a_g2 = (const float*)d_in[16];
    const float* a_be2 = (const float*)d_in[17];
    const float* att_Wq = (const float*)d_in[18];
    const float* att_bq = (const float*)d_in[19];
    const float* att_Wk = (const float*)d_in[20];
    const float* att_bk = (const float*)d_in[21];
    const float* att_Wv = (const float*)d_in[22];
    const float* att_bv = (const float*)d_in[23];
    const float* att_Wo = (const float*)d_in[24];
    const float* att_bo = (const float*)d_in[25];

    float* out = (float*)d_out;

    // ws layout (floats)
    float* ws      = (float*)d_ws;
    float* map_emb = ws;                          // 32*128*64
    float* target  = map_emb + BB * MM * EE;      // 32*64
    float* Qb      = target + BB * EE;            // 32*128*64
    float* Kb      = Qb + BB * MM * EE;           // 32*129*64
    float* Vb      = Kb + BB * 129 * EE;          // 32*129*64
    float* K2      = Vb + BB * 129 * EE;          // 32*128*64
    float* V2      = K2 + BB * MM * EE;           // 32*128*64

    const float* Wq0 = att_Wq + 0 * EE * EE; const float* bq0 = att_bq + 0 * EE;
    const float* Wk0 = att_Wk + 0 * EE * EE; const float* bk0 = att_bk + 0 * EE;
    const float* Wv0 = att_Wv + 0 * EE * EE; const float* bv0 = att_bv + 0 * EE;
    const float* Wo0 = att_Wo + 0 * EE * EE; const float* bo0 = att_bo + 0 * EE;
    const float* Wv1 = att_Wv + 1 * EE * EE; const float* bv1 = att_bv + 1 * EE;
    const float* Wo1 = att_Wo + 1 * EE * EE; const float* bo1 = att_bo + 1 * EE;
    const float* Wq2 = att_Wq + 2 * EE * EE; const float* bq2 = att_bq + 2 * EE;
    const float* Wk2 = att_Wk + 2 * EE * EE; const float* bk2 = att_bk + 2 * EE;
    const float* Wv2 = att_Wv + 2 * EE * EE; const float* bv2 = att_bv + 2 * EE;
    const float* Wo2 = att_Wo + 2 * EE * EE; const float* bo2 = att_bo + 2 * EE;

    // 1. fused local graphs + QKV projections (map: 4096 blocks, agent: 32)
    hipLaunchKernelGGL(lg_qkv_kernel, dim3(BB * MM + BB), dim3(128), 0, stream,
                       map_states, agent_states,
                       m_W1, m_b1, m_g1, m_be1, m_W2, m_b2, m_g2, m_be2,
                       a_W1, a_b1, a_g1, a_be1, a_W2, a_b2, a_g2, a_be2,
                       Wq0, bq0, Wk0, bk0, Wv0, bv0,
                       map_emb, target, Qb, Kb, Vb);

    // 2. a2m attention + residual + fused K2/V2
    hipLaunchKernelGGL(attn_fused_kernel, dim3(BB * MM), dim3(64), 0, stream,
                       map_emb, Qb, Kb, Vb, Wo0, bo0,
                       Wk2, bk2, Wv2, bv2, K2, V2, out);

    // 3. target row
    hipLaunchKernelGGL(target_kernel, dim3(BB), dim3(64), 0, stream,
                       target, K2, V2, Wq2, bq2, Wo2, bo2, Wv1, bv1, Wo1, bo1, out);
}

// Round 6
// 179.979 us; speedup vs baseline: 1.4799x; 1.0289x over previous
//
#include <hip/hip_runtime.h>

// Sizes (fixed by the problem)
#define BB 32
#define MM 128
#define PP 20
#define AA 32
#define TT 32
#define HH 32
#define EE 64

// ---------------------------------------------------------------------------
// Vectorized 64x64 matvec: out[c] = sum_i x[i] * W[i][c].
// Lane decomposition within a 64-lane wave: s = lane>>4, t = lane&15
// (4 channels 4t..4t+3). Returns fully-reduced float4 (valid in ALL lanes).
// W row-major [64][64]. xrow may be LDS or global.
// ---------------------------------------------------------------------------
__device__ __forceinline__ float4 matvec64(const float* __restrict__ W,
                                           const float* __restrict__ xrow,
                                           int s, int t)
{
    const float4* __restrict__ Wv = (const float4*)W;
    const float4* __restrict__ xv = (const float4*)xrow;
    float4 acc = make_float4(0.f, 0.f, 0.f, 0.f);
#pragma unroll
    for (int ii = 0; ii < 4; ++ii) {
        const float4 xx = xv[s * 4 + ii];
        const int ib = s * 16 + ii * 4;
        const float4 w0 = Wv[(ib + 0) * 16 + t];
        const float4 w1 = Wv[(ib + 1) * 16 + t];
        const float4 w2 = Wv[(ib + 2) * 16 + t];
        const float4 w3 = Wv[(ib + 3) * 16 + t];
        acc.x = fmaf(xx.x, w0.x, acc.x); acc.y = fmaf(xx.x, w0.y, acc.y);
        acc.z = fmaf(xx.x, w0.z, acc.z); acc.w = fmaf(xx.x, w0.w, acc.w);
        acc.x = fmaf(xx.y, w1.x, acc.x); acc.y = fmaf(xx.y, w1.y, acc.y);
        acc.z = fmaf(xx.y, w1.z, acc.z); acc.w = fmaf(xx.y, w1.w, acc.w);
        acc.x = fmaf(xx.z, w2.x, acc.x); acc.y = fmaf(xx.z, w2.y, acc.y);
        acc.z = fmaf(xx.z, w2.z, acc.z); acc.w = fmaf(xx.z, w2.w, acc.w);
        acc.x = fmaf(xx.w, w3.x, acc.x); acc.y = fmaf(xx.w, w3.y, acc.y);
        acc.z = fmaf(xx.w, w3.z, acc.z); acc.w = fmaf(xx.w, w3.w, acc.w);
    }
    acc.x += __shfl_xor(acc.x, 16); acc.y += __shfl_xor(acc.y, 16);
    acc.z += __shfl_xor(acc.z, 16); acc.w += __shfl_xor(acc.w, 16);
    acc.x += __shfl_xor(acc.x, 32); acc.y += __shfl_xor(acc.y, 32);
    acc.z += __shfl_xor(acc.z, 32); acc.w += __shfl_xor(acc.w, 32);
    return acc;
}

// ---------------------------------------------------------------------------
// Fused local-graph + QKV projection kernel. 256 threads (4 waves), 8 points
// in flight (sub = tid>>5). LN latency halved via var = E[h^2] - mu^2 with
// interleaved sum/sumsq shfl chains. All x loads hoisted to kernel entry.
// Exact simplification: neighbor-max half == plain max half for P>=2, e>=0.
// ---------------------------------------------------------------------------
template <int IN, int P>
__device__ __forceinline__ void lg_qkv_body(const float* __restrict__ xg,
                                            const float* __restrict__ W1, const float* __restrict__ b1,
                                            const float* __restrict__ g1, const float* __restrict__ be1,
                                            const float* __restrict__ W2, const float* __restrict__ b2,
                                            const float* __restrict__ g2, const float* __restrict__ be2,
                                            float* __restrict__ embRow,
                                            const float* __restrict__ Wq, const float* __restrict__ bq,
                                            const float* __restrict__ Wk, const float* __restrict__ bk,
                                            const float* __restrict__ Wv, const float* __restrict__ bv,
                                            float* __restrict__ Qrow,     // nullptr for agent
                                            float* __restrict__ Krow,
                                            float* __restrict__ Vrow)
{
    constexpr int NPASS = (P + 7) / 8;
    const int tid  = threadIdx.x;      // 0..255
    const int wave = tid >> 6;         // 0..3
    const int lane = tid & 63;
    const int sub  = tid >> 5;         // 0..7
    const int c    = tid & 31;

    __shared__ __align__(16) float aslot[8][32];
    __shared__ __align__(16) float wmax[4][32];
    __shared__ __align__(16) float xrow[EE];

    // ---- hoisted x loads: all passes' point data into registers ----
    float4 xr[NPASS][IN / 4];
#pragma unroll
    for (int ps = 0; ps < NPASS; ++ps) {
        int p = ps * 8 + sub;
        if (p > P - 1) p = P - 1;                 // clamp (masked out of max)
        const float4* xp4 = (const float4*)(xg + (long)p * IN);
#pragma unroll
        for (int j = 0; j < IN / 4; ++j) xr[ps][j] = xp4[j];
    }

    // ---- weight columns for this lane's channel c ----
    float w1c[IN];
#pragma unroll
    for (int k = 0; k < IN; ++k) w1c[k] = W1[k * HH + c];
    float w2c[HH];
#pragma unroll
    for (int k = 0; k < HH; ++k) w2c[k] = W2[k * HH + c];
    const float b1c = b1[c], g1c = g1[c], be1c = be1[c];
    const float b2c = b2[c], g2c = g2[c], be2c = be2[c];

    float cmax = -1e30f;

#pragma unroll
    for (int ps = 0; ps < NPASS; ++ps) {
        const bool valid = (ps * 8 + sub) < P;

        // layer 1: two accumulator chains
        float ha = b1c, hb = 0.0f;
#pragma unroll
        for (int j = 0; j < IN / 4; ++j) {
            const float4 xx = xr[ps][j];
            ha = fmaf(xx.x, w1c[4 * j + 0], ha);
            hb = fmaf(xx.y, w1c[4 * j + 1], hb);
            ha = fmaf(xx.z, w1c[4 * j + 2], ha);
            hb = fmaf(xx.w, w1c[4 * j + 3], hb);
        }
        const float h = ha + hb;

        // LN1: var = E[h^2] - mu^2, sum/sumsq chains interleaved
        float s1 = h, s2 = h * h;
#pragma unroll
        for (int off = 16; off >= 1; off >>= 1) {
            s1 += __shfl_xor(s1, off, 32);
            s2 += __shfl_xor(s2, off, 32);
        }
        const float mu  = s1 * (1.0f / 32.0f);
        float var = s2 * (1.0f / 32.0f) - mu * mu;
        var = fmaxf(var, 0.0f);
        float a = (h - mu) * rsqrtf(var + 1e-5f) * g1c + be1c;
        a = fmaxf(a, 0.0f);

        // layer 2 via LDS broadcast (same-sub producer/consumer, no barrier)
        aslot[sub][c] = a;
        const float4* av4 = (const float4*)aslot[sub];
        float h2a = b2c, h2b = 0.0f;
#pragma unroll
        for (int j = 0; j < 8; ++j) {
            const float4 aa = av4[j];
            h2a = fmaf(aa.x, w2c[4 * j + 0], h2a);
            h2b = fmaf(aa.y, w2c[4 * j + 1], h2b);
            h2a = fmaf(aa.z, w2c[4 * j + 2], h2a);
            h2b = fmaf(aa.w, w2c[4 * j + 3], h2b);
        }
        const float h2 = h2a + h2b;

        // LN2
        float t1 = h2, t2 = h2 * h2;
#pragma unroll
        for (int off = 16; off >= 1; off >>= 1) {
            t1 += __shfl_xor(t1, off, 32);
            t2 += __shfl_xor(t2, off, 32);
        }
        const float mu2  = t1 * (1.0f / 32.0f);
        float var2 = t2 * (1.0f / 32.0f) - mu2 * mu2;
        var2 = fmaxf(var2, 0.0f);
        float e = (h2 - mu2) * rsqrtf(var2 + 1e-5f) * g2c + be2c;
        e = fmaxf(e, 0.0f);

        if (valid) cmax = fmaxf(cmax, e);
    }

    // combine sub pairs within each wave, then across the 4 waves via LDS
    cmax = fmaxf(cmax, __shfl_xor(cmax, 32));
    if (lane < 32) wmax[wave][lane] = cmax;
    __syncthreads();

    if (tid < 32) {
        float fin = fmaxf(fmaxf(wmax[0][tid], wmax[1][tid]),
                          fmaxf(wmax[2][tid], wmax[3][tid]));
        xrow[tid]      = fin;
        xrow[tid + 32] = fin;
        embRow[tid]      = fin;
        embRow[tid + 32] = fin;
    }
    __syncthreads();

    // QKV projections: wave0 -> Q (map only), wave1 -> K, wave2 -> V
    const int s = lane >> 4, t = lane & 15;
    if (wave == 0) {
        if (Qrow) {
            float4 q4 = matvec64(Wq, xrow, s, t);
            if (s == 0) {
                const float4 bq4 = ((const float4*)bq)[t];
                float4 qo;
                qo.x = (q4.x + bq4.x) * 0.125f;
                qo.y = (q4.y + bq4.y) * 0.125f;
                qo.z = (q4.z + bq4.z) * 0.125f;
                qo.w = (q4.w + bq4.w) * 0.125f;
                ((float4*)Qrow)[t] = qo;
            }
        }
    } else if (wave == 1) {
        float4 k4 = matvec64(Wk, xrow, s, t);
        if (s == 0) {
            const float4 kb4 = ((const float4*)bk)[t];
            float4 ko;
            ko.x = k4.x + kb4.x; ko.y = k4.y + kb4.y;
            ko.z = k4.z + kb4.z; ko.w = k4.w + kb4.w;
            ((float4*)Krow)[t] = ko;
        }
    } else if (wave == 2) {
        float4 v4 = matvec64(Wv, xrow, s, t);
        if (s == 0) {
            const float4 vb4 = ((const float4*)bv)[t];
            float4 vo;
            vo.x = v4.x + vb4.x; vo.y = v4.y + vb4.y;
            vo.z = v4.z + vb4.z; vo.w = v4.w + vb4.w;
            ((float4*)Vrow)[t] = vo;
        }
    }
}

__global__ __launch_bounds__(256) void lg_qkv_kernel(
                              const float* __restrict__ map_states,
                              const float* __restrict__ agent_states,
                              const float* __restrict__ mW1, const float* __restrict__ mb1,
                              const float* __restrict__ mg1, const float* __restrict__ mbe1,
                              const float* __restrict__ mW2, const float* __restrict__ mb2,
                              const float* __restrict__ mg2, const float* __restrict__ mbe2,
                              const float* __restrict__ aW1, const float* __restrict__ ab1,
                              const float* __restrict__ ag1, const float* __restrict__ abe1,
                              const float* __restrict__ aW2, const float* __restrict__ ab2,
                              const float* __restrict__ ag2, const float* __restrict__ abe2,
                              const float* __restrict__ Wq, const float* __restrict__ bq,
                              const float* __restrict__ Wk, const float* __restrict__ bk,
                              const float* __restrict__ Wv, const float* __restrict__ bv,
                              float* __restrict__ map_emb,
                              float* __restrict__ target,
                              float* __restrict__ Qb,
                              float* __restrict__ Kb,
                              float* __restrict__ Vb)
{
    const int g = blockIdx.x;
    if (g < BB * MM) {
        const int b = g >> 7, m = g & 127;
        lg_qkv_body<16, PP>(map_states + (long)g * PP * 16,
                        mW1, mb1, mg1, mbe1, mW2, mb2, mg2, mbe2,
                        map_emb + (long)g * EE,
                        Wq, bq, Wk, bk, Wv, bv,
                        Qb + (long)g * EE,
                        Kb + ((long)b * 129 + 1 + m) * EE,
                        Vb + ((long)b * 129 + 1 + m) * EE);
    } else {
        const int b = g - BB * MM;
        lg_qkv_body<4, TT>(agent_states + (long)b * AA * TT * 4,
                       aW1, ab1, ag1, abe1, aW2, ab2, ag2, abe2,
                       target + (long)b * EE,
                       Wq, bq, Wk, bk, Wv, bv,
                       nullptr,
                       Kb + (long)b * 129 * EE,
                       Vb + (long)b * 129 * EE);
    }
}

// ---------------------------------------------------------------------------
// a2m attention: loads precomputed Q, scores (coalesced float4 K), softmax,
// PV (coalesced float4 V + shfl reduce), output proj + residual -> d_out rows
// 1..128, fused K2/V2 projection of the result row.
// One block (1 wave) per (b, query). NO cross-block sync (fences cost more
// than a kernel boundary — measured R4: +82 µs from per-block __threadfence).
// ---------------------------------------------------------------------------
__global__ void attn_fused_kernel(const float* __restrict__ map_emb,
                                  const float* __restrict__ Qb,
                                  const float* __restrict__ Kb,
                                  const float* __restrict__ Vb,
                                  const float* __restrict__ Wo, const float* __restrict__ bo,
                                  const float* __restrict__ Wk2, const float* __restrict__ bk2,
                                  const float* __restrict__ Wv2, const float* __restrict__ bv2,
                                  float* __restrict__ K2,   // [B,128,64]
                                  float* __restrict__ V2,   // [B,128,64]
                                  float* __restrict__ out)  // [B,129,64]
{
    const int blk  = blockIdx.x;
    const int b    = blk >> 7;
    const int q    = blk & 127;
    const int lane = threadIdx.x;
    const int s = lane >> 4, t = lane & 15;

    __shared__ __align__(16) float sc[132];
    __shared__ __align__(16) float av[EE];
    __shared__ __align__(16) float resrow[EE];

    const float4 q4 = ((const float4*)(Qb + ((long)b * MM + q) * EE))[t];

    // ---- scores: 4 keys/iter (j = 4*it + s), coalesced float4 K reads ----
    const float* Kbase = Kb + (long)b * 129 * EE;
    float mx = -1e30f;
#pragma unroll 4
    for (int it = 0; it < 33; ++it) {
        const int j = it * 4 + s;
        const bool valid = (j < 129);
        float p = 0.0f;
        if (valid) {
            const float4 k4 = ((const float4*)(Kbase + (long)j * EE))[t];
            p = q4.x * k4.x + q4.y * k4.y + q4.z * k4.z + q4.w * k4.w;
        }
        p += __shfl_xor(p, 1); p += __shfl_xor(p, 2);
        p += __shfl_xor(p, 4); p += __shfl_xor(p, 8);
        if (valid) {
            mx = fmaxf(mx, p);
            if (t == 0) sc[j] = p;
        }
    }
#pragma unroll
    for (int off = 32; off >= 1; off >>= 1) mx = fmaxf(mx, __shfl_xor(mx, off));
    __syncthreads();

    float sum = 0.0f;
    for (int j = lane; j < 129; j += 64) {
        const float e = __expf(sc[j] - mx);
        sc[j] = e;
        sum += e;
    }
#pragma unroll
    for (int off = 32; off >= 1; off >>= 1) sum += __shfl_xor(sum, off);
    const float inv = 1.0f / sum;
    __syncthreads();

    // ---- PV: float4 V reads (j = 4*it + s), reduce across s ----
    const float* Vbase = Vb + (long)b * 129 * EE;
    float4 a4 = make_float4(0.f, 0.f, 0.f, 0.f);
#pragma unroll 4
    for (int it = 0; it < 33; ++it) {
        const int j = it * 4 + s;
        if (j < 129) {
            const float w = sc[j];
            const float4 v4 = ((const float4*)(Vbase + (long)j * EE))[t];
            a4.x = fmaf(w, v4.x, a4.x); a4.y = fmaf(w, v4.y, a4.y);
            a4.z = fmaf(w, v4.z, a4.z); a4.w = fmaf(w, v4.w, a4.w);
        }
    }
    a4.x += __shfl_xor(a4.x, 16); a4.y += __shfl_xor(a4.y, 16);
    a4.z += __shfl_xor(a4.z, 16); a4.w += __shfl_xor(a4.w, 16);
    a4.x += __shfl_xor(a4.x, 32); a4.y += __shfl_xor(a4.y, 32);
    a4.z += __shfl_xor(a4.z, 32); a4.w += __shfl_xor(a4.w, 32);
    if (s == 0) {
        float4 o; o.x = a4.x * inv; o.y = a4.y * inv; o.z = a4.z * inv; o.w = a4.w * inv;
        ((float4*)av)[t] = o;
    }
    __syncthreads();

    // ---- output projection + residual ----
    const float4 o4 = matvec64(Wo, av, s, t);
    const float4 bo4 = ((const float4*)bo)[t];
    const float4 x4 = ((const float4*)(map_emb + ((long)b * MM + q) * EE))[t];
    float4 res;
    res.x = o4.x + bo4.x + x4.x;
    res.y = o4.y + bo4.y + x4.y;
    res.z = o4.z + bo4.z + x4.z;
    res.w = o4.w + bo4.w + x4.w;
    if (s == 0) {
        ((float4*)(out + ((long)b * 129 + 1 + q) * EE))[t] = res;
        ((float4*)resrow)[t] = res;
    }
    __syncthreads();

    // ---- fused K2/V2 projection of the result row ----
    const float4 k4 = matvec64(Wk2, resrow, s, t);
    const float4 v4 = matvec64(Wv2, resrow, s, t);
    if (s == 0) {
        const float4 kb4 = ((const float4*)bk2)[t];
        const float4 vb4 = ((const float4*)bv2)[t];
        float4 ko, vo;
        ko.x = k4.x + kb4.x; ko.y = k4.y + kb4.y; ko.z = k4.z + kb4.z; ko.w = k4.w + kb4.w;
        vo.x = v4.x + vb4.x; vo.y = v4.y + vb4.y; vo.z = v4.z + vb4.z; vo.w = v4.w + vb4.w;
        ((float4*)(K2 + ((long)b * MM + q) * EE))[t] = ko;
        ((float4*)(V2 + ((long)b * MM + q) * EE))[t] = vo;
    }
}

// ---------------------------------------------------------------------------
// Target row: t_a (exact single-token shortcut) + t_m2a attention over 128
// map tokens. One block (1 wave) per batch. Writes d_out row 0.
// ---------------------------------------------------------------------------
__global__ void target_kernel(const float* __restrict__ target,
                              const float* __restrict__ K2, const float* __restrict__ V2,
                              const float* __restrict__ Wq2, const float* __restrict__ bq2,
                              const float* __restrict__ Wo2, const float* __restrict__ bo2,
                              const float* __restrict__ Wv1, const float* __restrict__ bv1,
                              const float* __restrict__ Wo1, const float* __restrict__ bo1,
                              float* __restrict__ out)
{
    const int b    = blockIdx.x;
    const int lane = threadIdx.x;
    const int s = lane >> 4, t = lane & 15;

    __shared__ __align__(16) float trow[EE];
    __shared__ __align__(16) float tmp[EE];
    __shared__ __align__(16) float sc[128];
    __shared__ __align__(16) float av[EE];

    trow[lane] = target[(long)b * EE + lane];
    __syncthreads();

    // t_a = (t @ Wv1 + bv1) @ Wo1 + bo1  (softmax over one key == 1)
    const float4 v1 = matvec64(Wv1, trow, s, t);
    if (s == 0) {
        const float4 bv4 = ((const float4*)bv1)[t];
        float4 w; w.x = v1.x + bv4.x; w.y = v1.y + bv4.y; w.z = v1.z + bv4.z; w.w = v1.w + bv4.w;
        ((float4*)tmp)[t] = w;
    }
    __syncthreads();
    float4 ta = matvec64(Wo1, tmp, s, t);
    {
        const float4 bo4 = ((const float4*)bo1)[t];
        ta.x += bo4.x; ta.y += bo4.y; ta.z += bo4.z; ta.w += bo4.w;
    }

    // t_m2a query (pre-scaled)
    float4 q4 = matvec64(Wq2, trow, s, t);
    {
        const float4 bq4 = ((const float4*)bq2)[t];
        q4.x = (q4.x + bq4.x) * 0.125f;
        q4.y = (q4.y + bq4.y) * 0.125f;
        q4.z = (q4.z + bq4.z) * 0.125f;
        q4.w = (q4.w + bq4.w) * 0.125f;
    }

    const float* Kbase = K2 + (long)b * MM * EE;
    float mx = -1e30f;
#pragma unroll 4
    for (int it = 0; it < 32; ++it) {
        const int j = it * 4 + s;
        const float4 k4 = ((const float4*)(Kbase + (long)j * EE))[t];
        float p = q4.x * k4.x + q4.y * k4.y + q4.z * k4.z + q4.w * k4.w;
        p += __shfl_xor(p, 1); p += __shfl_xor(p, 2);
        p += __shfl_xor(p, 4); p += __shfl_xor(p, 8);
        mx = fmaxf(mx, p);
        if (t == 0) sc[j] = p;
    }
#pragma unroll
    for (int off = 32; off >= 1; off >>= 1) mx = fmaxf(mx, __shfl_xor(mx, off));
    __syncthreads();

    float sum = 0.0f;
#pragma unroll
    for (int j = lane; j < MM; j += 64) {
        const float e = __expf(sc[j] - mx);
        sc[j] = e;
        sum += e;
    }
#pragma unroll
    for (int off = 32; off >= 1; off >>= 1) sum += __shfl_xor(sum, off);
    const float inv = 1.0f / sum;
    __syncthreads();

    // PV: float4 V reads, reduce across s
    const float* Vbase = V2 + (long)b * MM * EE;
    float4 b4 = make_float4(0.f, 0.f, 0.f, 0.f);
#pragma unroll 4
    for (int it = 0; it < 32; ++it) {
        const int j = it * 4 + s;
        const float w = sc[j];
        const float4 vv = ((const float4*)(Vbase + (long)j * EE))[t];
        b4.x = fmaf(w, vv.x, b4.x); b4.y = fmaf(w, vv.y, b4.y);
        b4.z = fmaf(w, vv.z, b4.z); b4.w = fmaf(w, vv.w, b4.w);
    }
    b4.x += __shfl_xor(b4.x, 16); b4.y += __shfl_xor(b4.y, 16);
    b4.z += __shfl_xor(b4.z, 16); b4.w += __shfl_xor(b4.w, 16);
    b4.x += __shfl_xor(b4.x, 32); b4.y += __shfl_xor(b4.y, 32);
    b4.z += __shfl_xor(b4.z, 32); b4.w += __shfl_xor(b4.w, 32);
    if (s == 0) {
        float4 o; o.x = b4.x * inv; o.y = b4.y * inv; o.z = b4.z * inv; o.w = b4.w * inv;
        ((float4*)av)[t] = o;
    }
    __syncthreads();

    const float4 o4 = matvec64(Wo2, av, s, t);
    if (s == 0) {
        const float4 bo4 = ((const float4*)bo2)[t];
        float4 r;
        r.x = ta.x + o4.x + bo4.x;
        r.y = ta.y + o4.y + bo4.y;
        r.z = ta.z + o4.z + bo4.z;
        r.w = ta.w + o4.w + bo4.w;
        ((float4*)(out + (long)b * 129 * EE))[t] = r;
    }
}

// ---------------------------------------------------------------------------
extern "C" void kernel_launch(void* const* d_in, const int* in_sizes, int n_in,
                              void* d_out, int out_size, void* d_ws, size_t ws_size,
                              hipStream_t stream)
{
    const float* map_states   = (const float*)d_in[0];
    const float* agent_states = (const float*)d_in[1];
    const float* m_W1 = (const float*)d_in[2];
    const float* m_b1 = (const float*)d_in[3];
    const float* m_g1 = (const float*)d_in[4];
    const float* m_be1 = (const float*)d_in[5];
    const float* m_W2 = (const float*)d_in[6];
    const float* m_b2 = (const float*)d_in[7];
    const float* m_g2 = (const float*)d_in[8];
    const float* m_be2 = (const float*)d_in[9];
    const float* a_W1 = (const float*)d_in[10];
    const float* a_b1 = (const float*)d_in[11];
    const float* a_g1 = (const float*)d_in[12];
    const float* a_be1 = (const float*)d_in[13];
    const float* a_W2 = (const float*)d_in[14];
    const float* a_b2 = (const float*)d_in[15];
    const float* a_g2 = (const float*)d_in[16];
    const float* a_be2 = (const float*)d_in[17];
    const float* att_Wq = (const float*)d_in[18];
    const float* att_bq = (const float*)d_in[19];
    const float* att_Wk = (const float*)d_in[20];
    const float* att_bk = (const float*)d_in[21];
    const float* att_Wv = (const float*)d_in[22];
    const float* att_bv = (const float*)d_in[23];
    const float* att_Wo = (const float*)d_in[24];
    const float* att_bo = (const float*)d_in[25];

    float* out = (float*)d_out;

    // ws layout (floats)
    float* ws      = (float*)d_ws;
    float* map_emb = ws;                          // 32*128*64
    float* target  = map_emb + BB * MM * EE;      // 32*64
    float* Qb      = target + BB * EE;            // 32*128*64
    float* Kb      = Qb + BB * MM * EE;           // 32*129*64
    float* Vb      = Kb + BB * 129 * EE;          // 32*129*64
    float* K2      = Vb + BB * 129 * EE;          // 32*128*64
    float* V2      = K2 + BB * MM * EE;           // 32*128*64

    const float* Wq0 = att_Wq + 0 * EE * EE; const float* bq0 = att_bq + 0 * EE;
    const float* Wk0 = att_Wk + 0 * EE * EE; const float* bk0 = att_bk + 0 * EE;
    const float* Wv0 = att_Wv + 0 * EE * EE; const float* bv0 = att_bv + 0 * EE;
    const float* Wo0 = att_Wo + 0 * EE * EE; const float* bo0 = att_bo + 0 * EE;
    const float* Wv1 = att_Wv + 1 * EE * EE; const float* bv1 = att_bv + 1 * EE;
    const float* Wo1 = att_Wo + 1 * EE * EE; const float* bo1 = att_bo + 1 * EE;
    const float* Wq2 = att_Wq + 2 * EE * EE; const float* bq2 = att_bq + 2 * EE;
    const float* Wk2 = att_Wk + 2 * EE * EE; const float* bk2 = att_bk + 2 * EE;
    const float* Wv2 = att_Wv + 2 * EE * EE; const float* bv2 = att_bv + 2 * EE;
    const float* Wo2 = att_Wo + 2 * EE * EE; const float* bo2 = att_bo + 2 * EE;

    // 1. fused local graphs + QKV projections (map: 4096 blocks, agent: 32)
    hipLaunchKernelGGL(lg_qkv_kernel, dim3(BB * MM + BB), dim3(256), 0, stream,
                       map_states, agent_states,
                       m_W1, m_b1, m_g1, m_be1, m_W2, m_b2, m_g2, m_be2,
                       a_W1, a_b1, a_g1, a_be1, a_W2, a_b2, a_g2, a_be2,
                       Wq0, bq0, Wk0, bk0, Wv0, bv0,
                       map_emb, target, Qb, Kb, Vb);

    // 2. a2m attention + residual + fused K2/V2
    hipLaunchKernelGGL(attn_fused_kernel, dim3(BB * MM), dim3(64), 0, stream,
                       map_emb, Qb, Kb, Vb, Wo0, bo0,
                       Wk2, bk2, Wv2, bv2, K2, V2, out);

    // 3. target row
    hipLaunchKernelGGL(target_kernel, dim3(BB), dim3(64), 0, stream,
                       target, K2, V2, Wq2, bq2, Wo2, bo2, Wv1, bv1, Wo1, bo1, out);
}

// Round 7
// 176.124 us; speedup vs baseline: 1.5123x; 1.0219x over previous
//
#include <hip/hip_runtime.h>

// Sizes (fixed by the problem)
#define BB 32
#define MM 128
#define PP 20
#define AA 32
#define TT 32
#define HH 32
#define EE 64

// ---------------------------------------------------------------------------
// Vectorized 64x64 matvec: out[c] = sum_i x[i] * W[i][c].
// Lane decomposition within a 64-lane wave: s = lane>>4, t = lane&15
// (4 channels 4t..4t+3). Returns fully-reduced float4 (valid in ALL lanes).
// W row-major [64][64]. xrow may be LDS or global.
// ---------------------------------------------------------------------------
__device__ __forceinline__ float4 matvec64(const float* __restrict__ W,
                                           const float* __restrict__ xrow,
                                           int s, int t)
{
    const float4* __restrict__ Wv = (const float4*)W;
    const float4* __restrict__ xv = (const float4*)xrow;
    float4 acc = make_float4(0.f, 0.f, 0.f, 0.f);
#pragma unroll
    for (int ii = 0; ii < 4; ++ii) {
        const float4 xx = xv[s * 4 + ii];
        const int ib = s * 16 + ii * 4;
        const float4 w0 = Wv[(ib + 0) * 16 + t];
        const float4 w1 = Wv[(ib + 1) * 16 + t];
        const float4 w2 = Wv[(ib + 2) * 16 + t];
        const float4 w3 = Wv[(ib + 3) * 16 + t];
        acc.x = fmaf(xx.x, w0.x, acc.x); acc.y = fmaf(xx.x, w0.y, acc.y);
        acc.z = fmaf(xx.x, w0.z, acc.z); acc.w = fmaf(xx.x, w0.w, acc.w);
        acc.x = fmaf(xx.y, w1.x, acc.x); acc.y = fmaf(xx.y, w1.y, acc.y);
        acc.z = fmaf(xx.y, w1.z, acc.z); acc.w = fmaf(xx.y, w1.w, acc.w);
        acc.x = fmaf(xx.z, w2.x, acc.x); acc.y = fmaf(xx.z, w2.y, acc.y);
        acc.z = fmaf(xx.z, w2.z, acc.z); acc.w = fmaf(xx.z, w2.w, acc.w);
        acc.x = fmaf(xx.w, w3.x, acc.x); acc.y = fmaf(xx.w, w3.y, acc.y);
        acc.z = fmaf(xx.w, w3.z, acc.z); acc.w = fmaf(xx.w, w3.w, acc.w);
    }
    acc.x += __shfl_xor(acc.x, 16); acc.y += __shfl_xor(acc.y, 16);
    acc.z += __shfl_xor(acc.z, 16); acc.w += __shfl_xor(acc.w, 16);
    acc.x += __shfl_xor(acc.x, 32); acc.y += __shfl_xor(acc.y, 32);
    acc.z += __shfl_xor(acc.z, 32); acc.w += __shfl_xor(acc.w, 32);
    return acc;
}

// ---------------------------------------------------------------------------
// Fused local-graph + QKV projection kernel. 256 threads (4 waves), 8 points
// in flight (sub = tid>>5). LN via var = E[h^2] - mu^2, interleaved shfl
// chains. All x loads hoisted. Exact simplification: neighbor-max half ==
// plain max half for P>=2, e>=0.
// ---------------------------------------------------------------------------
template <int IN, int P>
__device__ __forceinline__ void lg_qkv_body(const float* __restrict__ xg,
                                            const float* __restrict__ W1, const float* __restrict__ b1,
                                            const float* __restrict__ g1, const float* __restrict__ be1,
                                            const float* __restrict__ W2, const float* __restrict__ b2,
                                            const float* __restrict__ g2, const float* __restrict__ be2,
                                            float* __restrict__ embRow,
                                            const float* __restrict__ Wq, const float* __restrict__ bq,
                                            const float* __restrict__ Wk, const float* __restrict__ bk,
                                            const float* __restrict__ Wv, const float* __restrict__ bv,
                                            float* __restrict__ Qrow,     // nullptr for agent
                                            float* __restrict__ Krow,
                                            float* __restrict__ Vrow)
{
    constexpr int NPASS = (P + 7) / 8;
    const int tid  = threadIdx.x;      // 0..255
    const int wave = tid >> 6;         // 0..3
    const int lane = tid & 63;
    const int sub  = tid >> 5;         // 0..7
    const int c    = tid & 31;

    __shared__ __align__(16) float aslot[8][32];
    __shared__ __align__(16) float wmax[4][32];
    __shared__ __align__(16) float xrow[EE];

    // hoisted x loads
    float4 xr[NPASS][IN / 4];
#pragma unroll
    for (int ps = 0; ps < NPASS; ++ps) {
        int p = ps * 8 + sub;
        if (p > P - 1) p = P - 1;                 // clamp (masked out of max)
        const float4* xp4 = (const float4*)(xg + (long)p * IN);
#pragma unroll
        for (int j = 0; j < IN / 4; ++j) xr[ps][j] = xp4[j];
    }

    float w1c[IN];
#pragma unroll
    for (int k = 0; k < IN; ++k) w1c[k] = W1[k * HH + c];
    float w2c[HH];
#pragma unroll
    for (int k = 0; k < HH; ++k) w2c[k] = W2[k * HH + c];
    const float b1c = b1[c], g1c = g1[c], be1c = be1[c];
    const float b2c = b2[c], g2c = g2[c], be2c = be2[c];

    float cmax = -1e30f;

#pragma unroll
    for (int ps = 0; ps < NPASS; ++ps) {
        const bool valid = (ps * 8 + sub) < P;

        float ha = b1c, hb = 0.0f;
#pragma unroll
        for (int j = 0; j < IN / 4; ++j) {
            const float4 xx = xr[ps][j];
            ha = fmaf(xx.x, w1c[4 * j + 0], ha);
            hb = fmaf(xx.y, w1c[4 * j + 1], hb);
            ha = fmaf(xx.z, w1c[4 * j + 2], ha);
            hb = fmaf(xx.w, w1c[4 * j + 3], hb);
        }
        const float h = ha + hb;

        float s1 = h, s2 = h * h;
#pragma unroll
        for (int off = 16; off >= 1; off >>= 1) {
            s1 += __shfl_xor(s1, off, 32);
            s2 += __shfl_xor(s2, off, 32);
        }
        const float mu  = s1 * (1.0f / 32.0f);
        float var = s2 * (1.0f / 32.0f) - mu * mu;
        var = fmaxf(var, 0.0f);
        float a = (h - mu) * rsqrtf(var + 1e-5f) * g1c + be1c;
        a = fmaxf(a, 0.0f);

        aslot[sub][c] = a;
        const float4* av4 = (const float4*)aslot[sub];
        float h2a = b2c, h2b = 0.0f;
#pragma unroll
        for (int j = 0; j < 8; ++j) {
            const float4 aa = av4[j];
            h2a = fmaf(aa.x, w2c[4 * j + 0], h2a);
            h2b = fmaf(aa.y, w2c[4 * j + 1], h2b);
            h2a = fmaf(aa.z, w2c[4 * j + 2], h2a);
            h2b = fmaf(aa.w, w2c[4 * j + 3], h2b);
        }
        const float h2 = h2a + h2b;

        float t1 = h2, t2 = h2 * h2;
#pragma unroll
        for (int off = 16; off >= 1; off >>= 1) {
            t1 += __shfl_xor(t1, off, 32);
            t2 += __shfl_xor(t2, off, 32);
        }
        const float mu2  = t1 * (1.0f / 32.0f);
        float var2 = t2 * (1.0f / 32.0f) - mu2 * mu2;
        var2 = fmaxf(var2, 0.0f);
        float e = (h2 - mu2) * rsqrtf(var2 + 1e-5f) * g2c + be2c;
        e = fmaxf(e, 0.0f);

        if (valid) cmax = fmaxf(cmax, e);
    }

    cmax = fmaxf(cmax, __shfl_xor(cmax, 32));
    if (lane < 32) wmax[wave][lane] = cmax;
    __syncthreads();

    if (tid < 32) {
        float fin = fmaxf(fmaxf(wmax[0][tid], wmax[1][tid]),
                          fmaxf(wmax[2][tid], wmax[3][tid]));
        xrow[tid]      = fin;
        xrow[tid + 32] = fin;
        embRow[tid]      = fin;
        embRow[tid + 32] = fin;
    }
    __syncthreads();

    const int s = lane >> 4, t = lane & 15;
    if (wave == 0) {
        if (Qrow) {
            float4 q4 = matvec64(Wq, xrow, s, t);
            if (s == 0) {
                const float4 bq4 = ((const float4*)bq)[t];
                float4 qo;
                qo.x = (q4.x + bq4.x) * 0.125f;
                qo.y = (q4.y + bq4.y) * 0.125f;
                qo.z = (q4.z + bq4.z) * 0.125f;
                qo.w = (q4.w + bq4.w) * 0.125f;
                ((float4*)Qrow)[t] = qo;
            }
        }
    } else if (wave == 1) {
        float4 k4 = matvec64(Wk, xrow, s, t);
        if (s == 0) {
            const float4 kb4 = ((const float4*)bk)[t];
            float4 ko;
            ko.x = k4.x + kb4.x; ko.y = k4.y + kb4.y;
            ko.z = k4.z + kb4.z; ko.w = k4.w + kb4.w;
            ((float4*)Krow)[t] = ko;
        }
    } else if (wave == 2) {
        float4 v4 = matvec64(Wv, xrow, s, t);
        if (s == 0) {
            const float4 vb4 = ((const float4*)bv)[t];
            float4 vo;
            vo.x = v4.x + vb4.x; vo.y = v4.y + vb4.y;
            vo.z = v4.z + vb4.z; vo.w = v4.w + vb4.w;
            ((float4*)Vrow)[t] = vo;
        }
    }
}

__global__ __launch_bounds__(256) void lg_qkv_kernel(
                              const float* __restrict__ map_states,
                              const float* __restrict__ agent_states,
                              const float* __restrict__ mW1, const float* __restrict__ mb1,
                              const float* __restrict__ mg1, const float* __restrict__ mbe1,
                              const float* __restrict__ mW2, const float* __restrict__ mb2,
                              const float* __restrict__ mg2, const float* __restrict__ mbe2,
                              const float* __restrict__ aW1, const float* __restrict__ ab1,
                              const float* __restrict__ ag1, const float* __restrict__ abe1,
                              const float* __restrict__ aW2, const float* __restrict__ ab2,
                              const float* __restrict__ ag2, const float* __restrict__ abe2,
                              const float* __restrict__ Wq, const float* __restrict__ bq,
                              const float* __restrict__ Wk, const float* __restrict__ bk,
                              const float* __restrict__ Wv, const float* __restrict__ bv,
                              float* __restrict__ map_emb,
                              float* __restrict__ target,
                              float* __restrict__ Qb,
                              float* __restrict__ Kb,
                              float* __restrict__ Vb)
{
    const int g = blockIdx.x;
    if (g < BB * MM) {
        const int b = g >> 7, m = g & 127;
        lg_qkv_body<16, PP>(map_states + (long)g * PP * 16,
                        mW1, mb1, mg1, mbe1, mW2, mb2, mg2, mbe2,
                        map_emb + (long)g * EE,
                        Wq, bq, Wk, bk, Wv, bv,
                        Qb + (long)g * EE,
                        Kb + ((long)b * 129 + 1 + m) * EE,
                        Vb + ((long)b * 129 + 1 + m) * EE);
    } else {
        const int b = g - BB * MM;
        lg_qkv_body<4, TT>(agent_states + (long)b * AA * TT * 4,
                       aW1, ab1, ag1, abe1, aW2, ab2, ag2, abe2,
                       target + (long)b * EE,
                       Wq, bq, Wk, bk, Wv, bv,
                       nullptr,
                       Kb + (long)b * 129 * EE,
                       Vb + (long)b * 129 * EE);
    }
}

// ---------------------------------------------------------------------------
// a2m attention: precomputed Q, coalesced float4 K/V, softmax, output proj +
// residual -> d_out rows 1..128. K2/V2 projections ELIMINATED algebraically
// (the t_m2a scores/values are linear in these rows — see target_kernel).
// One block (1 wave) per (b, query).
// ---------------------------------------------------------------------------
__global__ void attn_fused_kernel(const float* __restrict__ map_emb,
                                  const float* __restrict__ Qb,
                                  const float* __restrict__ Kb,
                                  const float* __restrict__ Vb,
                                  const float* __restrict__ Wo, const float* __restrict__ bo,
                                  float* __restrict__ out)  // [B,129,64]
{
    const int blk  = blockIdx.x;
    const int b    = blk >> 7;
    const int q    = blk & 127;
    const int lane = threadIdx.x;
    const int s = lane >> 4, t = lane & 15;

    __shared__ __align__(16) float sc[132];
    __shared__ __align__(16) float av[EE];

    const float4 q4 = ((const float4*)(Qb + ((long)b * MM + q) * EE))[t];

    // scores: j = 4*it + s, coalesced float4 K reads
    const float* Kbase = Kb + (long)b * 129 * EE;
    float mx = -1e30f;
#pragma unroll 4
    for (int it = 0; it < 33; ++it) {
        const int j = it * 4 + s;
        const bool valid = (j < 129);
        float p = 0.0f;
        if (valid) {
            const float4 k4 = ((const float4*)(Kbase + (long)j * EE))[t];
            p = q4.x * k4.x + q4.y * k4.y + q4.z * k4.z + q4.w * k4.w;
        }
        p += __shfl_xor(p, 1); p += __shfl_xor(p, 2);
        p += __shfl_xor(p, 4); p += __shfl_xor(p, 8);
        if (valid) {
            mx = fmaxf(mx, p);
            if (t == 0) sc[j] = p;
        }
    }
#pragma unroll
    for (int off = 32; off >= 1; off >>= 1) mx = fmaxf(mx, __shfl_xor(mx, off));
    __syncthreads();

    float sum = 0.0f;
    for (int j = lane; j < 129; j += 64) {
        const float e = __expf(sc[j] - mx);
        sc[j] = e;
        sum += e;
    }
#pragma unroll
    for (int off = 32; off >= 1; off >>= 1) sum += __shfl_xor(sum, off);
    const float inv = 1.0f / sum;
    __syncthreads();

    // PV: float4 V reads (j = 4*it + s), reduce across s
    const float* Vbase = Vb + (long)b * 129 * EE;
    float4 a4 = make_float4(0.f, 0.f, 0.f, 0.f);
#pragma unroll 4
    for (int it = 0; it < 33; ++it) {
        const int j = it * 4 + s;
        if (j < 129) {
            const float w = sc[j];
            const float4 v4 = ((const float4*)(Vbase + (long)j * EE))[t];
            a4.x = fmaf(w, v4.x, a4.x); a4.y = fmaf(w, v4.y, a4.y);
            a4.z = fmaf(w, v4.z, a4.z); a4.w = fmaf(w, v4.w, a4.w);
        }
    }
    a4.x += __shfl_xor(a4.x, 16); a4.y += __shfl_xor(a4.y, 16);
    a4.z += __shfl_xor(a4.z, 16); a4.w += __shfl_xor(a4.w, 16);
    a4.x += __shfl_xor(a4.x, 32); a4.y += __shfl_xor(a4.y, 32);
    a4.z += __shfl_xor(a4.z, 32); a4.w += __shfl_xor(a4.w, 32);
    if (s == 0) {
        float4 o; o.x = a4.x * inv; o.y = a4.y * inv; o.z = a4.z * inv; o.w = a4.w * inv;
        ((float4*)av)[t] = o;
    }
    __syncthreads();

    // output projection + residual -> d_out
    const float4 o4 = matvec64(Wo, av, s, t);
    if (s == 0) {
        const float4 bo4 = ((const float4*)bo)[t];
        const float4 x4 = ((const float4*)(map_emb + ((long)b * MM + q) * EE))[t];
        float4 res;
        res.x = o4.x + bo4.x + x4.x;
        res.y = o4.y + bo4.y + x4.y;
        res.z = o4.z + bo4.z + x4.z;
        res.w = o4.w + bo4.w + x4.w;
        ((float4*)(out + ((long)b * 129 + 1 + q) * EE))[t] = res;
    }
}

// ---------------------------------------------------------------------------
// Target row. t_a (exact single-token shortcut) + t_m2a over the 128 res
// rows in d_out, WITHOUT K2/V2:
//   score_j = (Wk2 qt) . res_j   (+ qt.bk2, j-independent -> cancels in softmax)
//   attnV   = Wv2^T (sum_j p_j res_j) + bv2     (sum p_j = 1)
// One block (1 wave) per batch. Writes d_out row 0.
// ---------------------------------------------------------------------------
__global__ void target_kernel(const float* __restrict__ target,
                              const float* __restrict__ Wq2, const float* __restrict__ bq2,
                              const float* __restrict__ Wk2,
                              const float* __restrict__ Wv2, const float* __restrict__ bv2,
                              const float* __restrict__ Wo2, const float* __restrict__ bo2,
                              const float* __restrict__ Wv1, const float* __restrict__ bv1,
                              const float* __restrict__ Wo1, const float* __restrict__ bo1,
                              float* __restrict__ out)   // [B,129,64]
{
    const int b    = blockIdx.x;
    const int lane = threadIdx.x;
    const int s = lane >> 4, t = lane & 15;

    __shared__ __align__(16) float trow[EE];
    __shared__ __align__(16) float tmp[EE];
    __shared__ __align__(16) float qtl[EE];
    __shared__ __align__(16) float qkl[EE];
    __shared__ __align__(16) float sc[128];
    __shared__ __align__(16) float av[EE];

    trow[lane] = target[(long)b * EE + lane];
    __syncthreads();

    // t_a = (t @ Wv1 + bv1) @ Wo1 + bo1  (softmax over one key == 1)
    const float4 v1 = matvec64(Wv1, trow, s, t);
    if (s == 0) {
        const float4 bv4 = ((const float4*)bv1)[t];
        float4 w; w.x = v1.x + bv4.x; w.y = v1.y + bv4.y; w.z = v1.z + bv4.z; w.w = v1.w + bv4.w;
        ((float4*)tmp)[t] = w;
    }
    __syncthreads();
    float4 ta = matvec64(Wo1, tmp, s, t);
    {
        const float4 bo4 = ((const float4*)bo1)[t];
        ta.x += bo4.x; ta.y += bo4.y; ta.z += bo4.z; ta.w += bo4.w;
    }

    // qt = (t @ Wq2 + bq2) / 8  -> LDS
    float4 q4 = matvec64(Wq2, trow, s, t);
    if (s == 0) {
        const float4 bq4 = ((const float4*)bq2)[t];
        float4 qo;
        qo.x = (q4.x + bq4.x) * 0.125f;
        qo.y = (q4.y + bq4.y) * 0.125f;
        qo.z = (q4.z + bq4.z) * 0.125f;
        qo.w = (q4.w + bq4.w) * 0.125f;
        ((float4*)qtl)[t] = qo;
    }
    __syncthreads();

    // qk[i] = sum_c Wk2[i][c] * qt[c]  (row i = lane)
    {
        const float4* Wrow = (const float4*)(Wk2 + (long)lane * EE);
        const float4* qt4  = (const float4*)qtl;
        float qa = 0.f, qb = 0.f;
#pragma unroll
        for (int j = 0; j < 16; j += 2) {
            const float4 w0 = Wrow[j],     x0 = qt4[j];
            const float4 w1 = Wrow[j + 1], x1 = qt4[j + 1];
            qa = fmaf(w0.x, x0.x, qa); qb = fmaf(w0.y, x0.y, qb);
            qa = fmaf(w0.z, x0.z, qa); qb = fmaf(w0.w, x0.w, qb);
            qa = fmaf(w1.x, x1.x, qa); qb = fmaf(w1.y, x1.y, qb);
            qa = fmaf(w1.z, x1.z, qa); qb = fmaf(w1.w, x1.w, qb);
        }
        qkl[lane] = qa + qb;
    }
    __syncthreads();

    // scores over res rows (d_out rows 1..128 of batch b)
    const float* Rbase = out + ((long)b * 129 + 1) * EE;
    const float4 qk4 = ((const float4*)qkl)[t];
    float mx = -1e30f;
#pragma unroll 4
    for (int it = 0; it < 32; ++it) {
        const int j = it * 4 + s;
        const float4 r4 = ((const float4*)(Rbase + (long)j * EE))[t];
        float p = qk4.x * r4.x + qk4.y * r4.y + qk4.z * r4.z + qk4.w * r4.w;
        p += __shfl_xor(p, 1); p += __shfl_xor(p, 2);
        p += __shfl_xor(p, 4); p += __shfl_xor(p, 8);
        mx = fmaxf(mx, p);
        if (t == 0) sc[j] = p;
    }
#pragma unroll
    for (int off = 32; off >= 1; off >>= 1) mx = fmaxf(mx, __shfl_xor(mx, off));
    __syncthreads();

    float sum = 0.0f;
#pragma unroll
    for (int j = lane; j < MM; j += 64) {
        const float e = __expf(sc[j] - mx);
        sc[j] = e;
        sum += e;
    }
#pragma unroll
    for (int off = 32; off >= 1; off >>= 1) sum += __shfl_xor(sum, off);
    const float inv = 1.0f / sum;
    __syncthreads();

    // rbar = sum_j p_j res_j
    float4 b4 = make_float4(0.f, 0.f, 0.f, 0.f);
#pragma unroll 4
    for (int it = 0; it < 32; ++it) {
        const int j = it * 4 + s;
        const float w = sc[j];
        const float4 rr = ((const float4*)(Rbase + (long)j * EE))[t];
        b4.x = fmaf(w, rr.x, b4.x); b4.y = fmaf(w, rr.y, b4.y);
        b4.z = fmaf(w, rr.z, b4.z); b4.w = fmaf(w, rr.w, b4.w);
    }
    b4.x += __shfl_xor(b4.x, 16); b4.y += __shfl_xor(b4.y, 16);
    b4.z += __shfl_xor(b4.z, 16); b4.w += __shfl_xor(b4.w, 16);
    b4.x += __shfl_xor(b4.x, 32); b4.y += __shfl_xor(b4.y, 32);
    b4.z += __shfl_xor(b4.z, 32); b4.w += __shfl_xor(b4.w, 32);
    if (s == 0) {
        float4 o; o.x = b4.x * inv; o.y = b4.y * inv; o.z = b4.z * inv; o.w = b4.w * inv;
        ((float4*)av)[t] = o;
    }
    __syncthreads();

    // attnV = rbar @ Wv2 + bv2 -> tmp
    const float4 vv = matvec64(Wv2, av, s, t);
    if (s == 0) {
        const float4 bv4 = ((const float4*)bv2)[t];
        float4 w; w.x = vv.x + bv4.x; w.y = vv.y + bv4.y; w.z = vv.z + bv4.z; w.w = vv.w + bv4.w;
        ((float4*)tmp)[t] = w;
    }
    __syncthreads();

    // row0 = t_a + attnV @ Wo2 + bo2
    const float4 o4 = matvec64(Wo2, tmp, s, t);
    if (s == 0) {
        const float4 bo4 = ((const float4*)bo2)[t];
        float4 r;
        r.x = ta.x + o4.x + bo4.x;
        r.y = ta.y + o4.y + bo4.y;
        r.z = ta.z + o4.z + bo4.z;
        r.w = ta.w + o4.w + bo4.w;
        ((float4*)(out + (long)b * 129 * EE))[t] = r;
    }
}

// ---------------------------------------------------------------------------
extern "C" void kernel_launch(void* const* d_in, const int* in_sizes, int n_in,
                              void* d_out, int out_size, void* d_ws, size_t ws_size,
                              hipStream_t stream)
{
    const float* map_states   = (const float*)d_in[0];
    const float* agent_states = (const float*)d_in[1];
    const float* m_W1 = (const float*)d_in[2];
    const float* m_b1 = (const float*)d_in[3];
    const float* m_g1 = (const float*)d_in[4];
    const float* m_be1 = (const float*)d_in[5];
    const float* m_W2 = (const float*)d_in[6];
    const float* m_b2 = (const float*)d_in[7];
    const float* m_g2 = (const float*)d_in[8];
    const float* m_be2 = (const float*)d_in[9];
    const float* a_W1 = (const float*)d_in[10];
    const float* a_b1 = (const float*)d_in[11];
    const float* a_g1 = (const float*)d_in[12];
    const float* a_be1 = (const float*)d_in[13];
    const float* a_W2 = (const float*)d_in[14];
    const float* a_b2 = (const float*)d_in[15];
    const float* a_g2 = (const float*)d_in[16];
    const float* a_be2 = (const float*)d_in[17];
    const float* att_Wq = (const float*)d_in[18];
    const float* att_bq = (const float*)d_in[19];
    const float* att_Wk = (const float*)d_in[20];
    const float* att_bk = (const float*)d_in[21];
    const float* att_Wv = (const float*)d_in[22];
    const float* att_bv = (const float*)d_in[23];
    const float* att_Wo = (const float*)d_in[24];
    const float* att_bo = (const float*)d_in[25];

    float* out = (float*)d_out;

    // ws layout (floats)
    float* ws      = (float*)d_ws;
    float* map_emb = ws;                          // 32*128*64
    float* target  = map_emb + BB * MM * EE;      // 32*64
    float* Qb      = target + BB * EE;            // 32*128*64
    float* Kb      = Qb + BB * MM * EE;           // 32*129*64
    float* Vb      = Kb + BB * 129 * EE;          // 32*129*64

    const float* Wq0 = att_Wq + 0 * EE * EE; const float* bq0 = att_bq + 0 * EE;
    const float* Wk0 = att_Wk + 0 * EE * EE; const float* bk0 = att_bk + 0 * EE;
    const float* Wv0 = att_Wv + 0 * EE * EE; const float* bv0 = att_bv + 0 * EE;
    const float* Wo0 = att_Wo + 0 * EE * EE; const float* bo0 = att_bo + 0 * EE;
    const float* Wv1 = att_Wv + 1 * EE * EE; const float* bv1 = att_bv + 1 * EE;
    const float* Wo1 = att_Wo + 1 * EE * EE; const float* bo1 = att_bo + 1 * EE;
    const float* Wq2 = att_Wq + 2 * EE * EE; const float* bq2 = att_bq + 2 * EE;
    const float* Wk2 = att_Wk + 2 * EE * EE;
    const float* Wv2 = att_Wv + 2 * EE * EE; const float* bv2 = att_bv + 2 * EE;
    const float* Wo2 = att_Wo + 2 * EE * EE; const float* bo2 = att_bo + 2 * EE;

    // 1. fused local graphs + QKV projections (map: 4096 blocks, agent: 32)
    hipLaunchKernelGGL(lg_qkv_kernel, dim3(BB * MM + BB), dim3(256), 0, stream,
                       map_states, agent_states,
                       m_W1, m_b1, m_g1, m_be1, m_W2, m_b2, m_g2, m_be2,
                       a_W1, a_b1, a_g1, a_be1, a_W2, a_b2, a_g2, a_be2,
                       Wq0, bq0, Wk0, bk0, Wv0, bv0,
                       map_emb, target, Qb, Kb, Vb);

    // 2. a2m attention + residual -> d_out rows 1..128
    hipLaunchKernelGGL(attn_fused_kernel, dim3(BB * MM), dim3(64), 0, stream,
                       map_emb, Qb, Kb, Vb, Wo0, bo0, out);

    // 3. target row (reads res rows from d_out; no K2/V2 needed)
    hipLaunchKernelGGL(target_kernel, dim3(BB), dim3(64), 0, stream,
                       target, Wq2, bq2, Wk2, Wv2, bv2, Wo2, bo2,
                       Wv1, bv1, Wo1, bo1, out);
}

// Round 8
// 175.340 us; speedup vs baseline: 1.5191x; 1.0045x over previous
//
#include <hip/hip_runtime.h>

// Sizes (fixed by the problem)
#define BB 32
#define MM 128
#define PP 20
#define AA 32
#define TT 32
#define HH 32
#define EE 64

// ---------------------------------------------------------------------------
// Vectorized 64x64 matvec: out[c] = sum_i x[i] * W[i][c].
// Lane decomposition within a 64-lane wave: s = lane>>4, t = lane&15
// (4 channels 4t..4t+3). Returns fully-reduced float4 (valid in ALL lanes).
// ---------------------------------------------------------------------------
__device__ __forceinline__ float4 matvec64(const float* __restrict__ W,
                                           const float* __restrict__ xrow,
                                           int s, int t)
{
    const float4* __restrict__ Wv = (const float4*)W;
    const float4* __restrict__ xv = (const float4*)xrow;
    float4 acc = make_float4(0.f, 0.f, 0.f, 0.f);
#pragma unroll
    for (int ii = 0; ii < 4; ++ii) {
        const float4 xx = xv[s * 4 + ii];
        const int ib = s * 16 + ii * 4;
        const float4 w0 = Wv[(ib + 0) * 16 + t];
        const float4 w1 = Wv[(ib + 1) * 16 + t];
        const float4 w2 = Wv[(ib + 2) * 16 + t];
        const float4 w3 = Wv[(ib + 3) * 16 + t];
        acc.x = fmaf(xx.x, w0.x, acc.x); acc.y = fmaf(xx.x, w0.y, acc.y);
        acc.z = fmaf(xx.x, w0.z, acc.z); acc.w = fmaf(xx.x, w0.w, acc.w);
        acc.x = fmaf(xx.y, w1.x, acc.x); acc.y = fmaf(xx.y, w1.y, acc.y);
        acc.z = fmaf(xx.y, w1.z, acc.z); acc.w = fmaf(xx.y, w1.w, acc.w);
        acc.x = fmaf(xx.z, w2.x, acc.x); acc.y = fmaf(xx.z, w2.y, acc.y);
        acc.z = fmaf(xx.z, w2.z, acc.z); acc.w = fmaf(xx.z, w2.w, acc.w);
        acc.x = fmaf(xx.w, w3.x, acc.x); acc.y = fmaf(xx.w, w3.y, acc.y);
        acc.z = fmaf(xx.w, w3.z, acc.z); acc.w = fmaf(xx.w, w3.w, acc.w);
    }
    acc.x += __shfl_xor(acc.x, 16); acc.y += __shfl_xor(acc.y, 16);
    acc.z += __shfl_xor(acc.z, 16); acc.w += __shfl_xor(acc.w, 16);
    acc.x += __shfl_xor(acc.x, 32); acc.y += __shfl_xor(acc.y, 32);
    acc.z += __shfl_xor(acc.z, 32); acc.w += __shfl_xor(acc.w, 32);
    return acc;
}

// ---------------------------------------------------------------------------
// Fused local-graph + QKV projection kernel. 320 threads (5 waves), 10 points
// in flight (sub = tid>>5): map P=20 -> exactly 2 passes, zero wasted slots.
// LN via var = E[h^2] - mu^2, interleaved shfl chains. x loads hoisted.
// Exact simplification: neighbor-max half == plain max half for P>=2, e>=0.
// ---------------------------------------------------------------------------
template <int IN, int P>
__device__ __forceinline__ void lg_qkv_body(const float* __restrict__ xg,
                                            const float* __restrict__ W1, const float* __restrict__ b1,
                                            const float* __restrict__ g1, const float* __restrict__ be1,
                                            const float* __restrict__ W2, const float* __restrict__ b2,
                                            const float* __restrict__ g2, const float* __restrict__ be2,
                                            float* __restrict__ embRow,
                                            const float* __restrict__ Wq, const float* __restrict__ bq,
                                            const float* __restrict__ Wk, const float* __restrict__ bk,
                                            const float* __restrict__ Wv, const float* __restrict__ bv,
                                            float* __restrict__ Qrow,     // nullptr for agent
                                            float* __restrict__ Krow,
                                            float* __restrict__ Vrow)
{
    constexpr int NSUB  = 10;
    constexpr int NPASS = (P + NSUB - 1) / NSUB;
    const int tid  = threadIdx.x;      // 0..319
    const int wave = tid >> 6;         // 0..4
    const int lane = tid & 63;
    const int sub  = tid >> 5;         // 0..9
    const int c    = tid & 31;

    __shared__ __align__(16) float aslot[NSUB][32];
    __shared__ __align__(16) float wmax[5][32];
    __shared__ __align__(16) float xrow[EE];

    // hoisted x loads
    float4 xr[NPASS][IN / 4];
#pragma unroll
    for (int ps = 0; ps < NPASS; ++ps) {
        int p = ps * NSUB + sub;
        if (p > P - 1) p = P - 1;                 // clamp (masked out of max)
        const float4* xp4 = (const float4*)(xg + (long)p * IN);
#pragma unroll
        for (int j = 0; j < IN / 4; ++j) xr[ps][j] = xp4[j];
    }

    float w1c[IN];
#pragma unroll
    for (int k = 0; k < IN; ++k) w1c[k] = W1[k * HH + c];
    float w2c[HH];
#pragma unroll
    for (int k = 0; k < HH; ++k) w2c[k] = W2[k * HH + c];
    const float b1c = b1[c], g1c = g1[c], be1c = be1[c];
    const float b2c = b2[c], g2c = g2[c], be2c = be2[c];

    float cmax = -1e30f;

#pragma unroll
    for (int ps = 0; ps < NPASS; ++ps) {
        const bool valid = (ps * NSUB + sub) < P;

        float ha = b1c, hb = 0.0f;
#pragma unroll
        for (int j = 0; j < IN / 4; ++j) {
            const float4 xx = xr[ps][j];
            ha = fmaf(xx.x, w1c[4 * j + 0], ha);
            hb = fmaf(xx.y, w1c[4 * j + 1], hb);
            ha = fmaf(xx.z, w1c[4 * j + 2], ha);
            hb = fmaf(xx.w, w1c[4 * j + 3], hb);
        }
        const float h = ha + hb;

        float s1 = h, s2 = h * h;
#pragma unroll
        for (int off = 16; off >= 1; off >>= 1) {
            s1 += __shfl_xor(s1, off, 32);
            s2 += __shfl_xor(s2, off, 32);
        }
        const float mu  = s1 * (1.0f / 32.0f);
        float var = s2 * (1.0f / 32.0f) - mu * mu;
        var = fmaxf(var, 0.0f);
        float a = (h - mu) * rsqrtf(var + 1e-5f) * g1c + be1c;
        a = fmaxf(a, 0.0f);

        // layer 2 via LDS broadcast (same-sub producer/consumer, no barrier)
        aslot[sub][c] = a;
        const float4* av4 = (const float4*)aslot[sub];
        float h2a = b2c, h2b = 0.0f;
#pragma unroll
        for (int j = 0; j < 8; ++j) {
            const float4 aa = av4[j];
            h2a = fmaf(aa.x, w2c[4 * j + 0], h2a);
            h2b = fmaf(aa.y, w2c[4 * j + 1], h2b);
            h2a = fmaf(aa.z, w2c[4 * j + 2], h2a);
            h2b = fmaf(aa.w, w2c[4 * j + 3], h2b);
        }
        const float h2 = h2a + h2b;

        float t1 = h2, t2 = h2 * h2;
#pragma unroll
        for (int off = 16; off >= 1; off >>= 1) {
            t1 += __shfl_xor(t1, off, 32);
            t2 += __shfl_xor(t2, off, 32);
        }
        const float mu2  = t1 * (1.0f / 32.0f);
        float var2 = t2 * (1.0f / 32.0f) - mu2 * mu2;
        var2 = fmaxf(var2, 0.0f);
        float e = (h2 - mu2) * rsqrtf(var2 + 1e-5f) * g2c + be2c;
        e = fmaxf(e, 0.0f);

        if (valid) cmax = fmaxf(cmax, e);
    }

    // combine sub pairs within each wave, then across the 5 waves via LDS
    cmax = fmaxf(cmax, __shfl_xor(cmax, 32));
    if (lane < 32) wmax[wave][lane] = cmax;
    __syncthreads();

    if (tid < 32) {
        float fin = fmaxf(fmaxf(fmaxf(wmax[0][tid], wmax[1][tid]),
                                fmaxf(wmax[2][tid], wmax[3][tid])),
                          wmax[4][tid]);
        xrow[tid]      = fin;
        xrow[tid + 32] = fin;
        embRow[tid]      = fin;
        embRow[tid + 32] = fin;
    }
    __syncthreads();

    const int s = lane >> 4, t = lane & 15;
    if (wave == 0) {
        if (Qrow) {
            float4 q4 = matvec64(Wq, xrow, s, t);
            if (s == 0) {
                const float4 bq4 = ((const float4*)bq)[t];
                float4 qo;
                qo.x = (q4.x + bq4.x) * 0.125f;
                qo.y = (q4.y + bq4.y) * 0.125f;
                qo.z = (q4.z + bq4.z) * 0.125f;
                qo.w = (q4.w + bq4.w) * 0.125f;
                ((float4*)Qrow)[t] = qo;
            }
        }
    } else if (wave == 1) {
        float4 k4 = matvec64(Wk, xrow, s, t);
        if (s == 0) {
            const float4 kb4 = ((const float4*)bk)[t];
            float4 ko;
            ko.x = k4.x + kb4.x; ko.y = k4.y + kb4.y;
            ko.z = k4.z + kb4.z; ko.w = k4.w + kb4.w;
            ((float4*)Krow)[t] = ko;
        }
    } else if (wave == 2) {
        float4 v4 = matvec64(Wv, xrow, s, t);
        if (s == 0) {
            const float4 vb4 = ((const float4*)bv)[t];
            float4 vo;
            vo.x = v4.x + vb4.x; vo.y = v4.y + vb4.y;
            vo.z = v4.z + vb4.z; vo.w = v4.w + vb4.w;
            ((float4*)Vrow)[t] = vo;
        }
    }
}

__global__ __launch_bounds__(320) void lg_qkv_kernel(
                              const float* __restrict__ map_states,
                              const float* __restrict__ agent_states,
                              const float* __restrict__ mW1, const float* __restrict__ mb1,
                              const float* __restrict__ mg1, const float* __restrict__ mbe1,
                              const float* __restrict__ mW2, const float* __restrict__ mb2,
                              const float* __restrict__ mg2, const float* __restrict__ mbe2,
                              const float* __restrict__ aW1, const float* __restrict__ ab1,
                              const float* __restrict__ ag1, const float* __restrict__ abe1,
                              const float* __restrict__ aW2, const float* __restrict__ ab2,
                              const float* __restrict__ ag2, const float* __restrict__ abe2,
                              const float* __restrict__ Wq, const float* __restrict__ bq,
                              const float* __restrict__ Wk, const float* __restrict__ bk,
                              const float* __restrict__ Wv, const float* __restrict__ bv,
                              float* __restrict__ map_emb,
                              float* __restrict__ target,
                              float* __restrict__ Qb,
                              float* __restrict__ Kb,
                              float* __restrict__ Vb)
{
    const int g = blockIdx.x;
    if (g < BB * MM) {
        const int b = g >> 7, m = g & 127;
        lg_qkv_body<16, PP>(map_states + (long)g * PP * 16,
                        mW1, mb1, mg1, mbe1, mW2, mb2, mg2, mbe2,
                        map_emb + (long)g * EE,
                        Wq, bq, Wk, bk, Wv, bv,
                        Qb + (long)g * EE,
                        Kb + ((long)b * 129 + 1 + m) * EE,
                        Vb + ((long)b * 129 + 1 + m) * EE);
    } else {
        const int b = g - BB * MM;
        lg_qkv_body<4, TT>(agent_states + (long)b * AA * TT * 4,
                       aW1, ab1, ag1, abe1, aW2, ab2, ag2, abe2,
                       target + (long)b * EE,
                       Wq, bq, Wk, bk, Wv, bv,
                       nullptr,
                       Kb + (long)b * 129 * EE,
                       Vb + (long)b * 129 * EE);
    }
}

// ---------------------------------------------------------------------------
// a2m attention, ONLINE softmax: single pass over K and V (running m/l/vacc
// per s-group, 4 keys in flight, merged by 2 shfl_xor state-merges), then
// output proj + residual -> d_out rows 1..128.
// One block (1 wave) per (b, query).
// ---------------------------------------------------------------------------
__global__ void attn_fused_kernel(const float* __restrict__ map_emb,
                                  const float* __restrict__ Qb,
                                  const float* __restrict__ Kb,
                                  const float* __restrict__ Vb,
                                  const float* __restrict__ Wo, const float* __restrict__ bo,
                                  float* __restrict__ out)  // [B,129,64]
{
    const int blk  = blockIdx.x;
    const int b    = blk >> 7;
    const int q    = blk & 127;
    const int lane = threadIdx.x;
    const int s = lane >> 4, t = lane & 15;

    __shared__ __align__(16) float av[EE];

    const float4 q4 = ((const float4*)(Qb + ((long)b * MM + q) * EE))[t];

    const float* Kbase = Kb + (long)b * 129 * EE;
    const float* Vbase = Vb + (long)b * 129 * EE;

    float m = -1e30f, l = 0.0f;
    float4 vacc = make_float4(0.f, 0.f, 0.f, 0.f);

#pragma unroll 4
    for (int it = 0; it < 33; ++it) {
        const int j = it * 4 + s;
        if (j < 129) {
            const float4 k4 = ((const float4*)(Kbase + (long)j * EE))[t];
            float p = q4.x * k4.x + q4.y * k4.y + q4.z * k4.z + q4.w * k4.w;
            p += __shfl_xor(p, 1); p += __shfl_xor(p, 2);
            p += __shfl_xor(p, 4); p += __shfl_xor(p, 8);
            const float4 v4 = ((const float4*)(Vbase + (long)j * EE))[t];
            const float mn    = fmaxf(m, p);
            const float alpha = __expf(m - mn);   // first iter: exp(-inf)=0
            const float e     = __expf(p - mn);
            l = l * alpha + e;
            vacc.x = fmaf(e, v4.x, vacc.x * alpha);
            vacc.y = fmaf(e, v4.y, vacc.y * alpha);
            vacc.z = fmaf(e, v4.z, vacc.z * alpha);
            vacc.w = fmaf(e, v4.w, vacc.w * alpha);
            m = mn;
        }
    }

    // merge softmax states across the 4 s-groups (lane bits 4 and 5)
#pragma unroll
    for (int off = 16; off <= 32; off <<= 1) {
        const float mo = __shfl_xor(m, off);
        const float lo = __shfl_xor(l, off);
        float4 vo;
        vo.x = __shfl_xor(vacc.x, off);
        vo.y = __shfl_xor(vacc.y, off);
        vo.z = __shfl_xor(vacc.z, off);
        vo.w = __shfl_xor(vacc.w, off);
        const float mn = fmaxf(m, mo);
        const float a  = __expf(m - mn);
        const float bb = __expf(mo - mn);
        l = l * a + lo * bb;
        vacc.x = vacc.x * a + vo.x * bb;
        vacc.y = vacc.y * a + vo.y * bb;
        vacc.z = vacc.z * a + vo.z * bb;
        vacc.w = vacc.w * a + vo.w * bb;
        m = mn;
    }
    const float inv = 1.0f / l;
    if (s == 0) {
        float4 o;
        o.x = vacc.x * inv; o.y = vacc.y * inv;
        o.z = vacc.z * inv; o.w = vacc.w * inv;
        ((float4*)av)[t] = o;
    }
    __syncthreads();

    // output projection + residual -> d_out
    const float4 o4 = matvec64(Wo, av, s, t);
    if (s == 0) {
        const float4 bo4 = ((const float4*)bo)[t];
        const float4 x4 = ((const float4*)(map_emb + ((long)b * MM + q) * EE))[t];
        float4 res;
        res.x = o4.x + bo4.x + x4.x;
        res.y = o4.y + bo4.y + x4.y;
        res.z = o4.z + bo4.z + x4.z;
        res.w = o4.w + bo4.w + x4.w;
        ((float4*)(out + ((long)b * 129 + 1 + q) * EE))[t] = res;
    }
}

// ---------------------------------------------------------------------------
// Target row. t_a (exact single-token shortcut) + t_m2a over the 128 res
// rows in d_out, WITHOUT K2/V2 (exact linear-algebra elimination):
//   score_j = (Wk2 qt) . res_j   (+ qt.bk2, j-independent -> cancels in softmax)
//   attnV   = Wv2^T (sum_j p_j res_j) + bv2     (sum p_j = 1)
// One block (1 wave) per batch. Writes d_out row 0.
// ---------------------------------------------------------------------------
__global__ void target_kernel(const float* __restrict__ target,
                              const float* __restrict__ Wq2, const float* __restrict__ bq2,
                              const float* __restrict__ Wk2,
                              const float* __restrict__ Wv2, const float* __restrict__ bv2,
                              const float* __restrict__ Wo2, const float* __restrict__ bo2,
                              const float* __restrict__ Wv1, const float* __restrict__ bv1,
                              const float* __restrict__ Wo1, const float* __restrict__ bo1,
                              float* __restrict__ out)   // [B,129,64]
{
    const int b    = blockIdx.x;
    const int lane = threadIdx.x;
    const int s = lane >> 4, t = lane & 15;

    __shared__ __align__(16) float trow[EE];
    __shared__ __align__(16) float tmp[EE];
    __shared__ __align__(16) float qtl[EE];
    __shared__ __align__(16) float qkl[EE];
    __shared__ __align__(16) float sc[128];
    __shared__ __align__(16) float av[EE];

    trow[lane] = target[(long)b * EE + lane];
    __syncthreads();

    // t_a = (t @ Wv1 + bv1) @ Wo1 + bo1  (softmax over one key == 1)
    const float4 v1 = matvec64(Wv1, trow, s, t);
    if (s == 0) {
        const float4 bv4 = ((const float4*)bv1)[t];
        float4 w; w.x = v1.x + bv4.x; w.y = v1.y + bv4.y; w.z = v1.z + bv4.z; w.w = v1.w + bv4.w;
        ((float4*)tmp)[t] = w;
    }
    __syncthreads();
    float4 ta = matvec64(Wo1, tmp, s, t);
    {
        const float4 bo4 = ((const float4*)bo1)[t];
        ta.x += bo4.x; ta.y += bo4.y; ta.z += bo4.z; ta.w += bo4.w;
    }

    // qt = (t @ Wq2 + bq2) / 8  -> LDS
    float4 q4 = matvec64(Wq2, trow, s, t);
    if (s == 0) {
        const float4 bq4 = ((const float4*)bq2)[t];
        float4 qo;
        qo.x = (q4.x + bq4.x) * 0.125f;
        qo.y = (q4.y + bq4.y) * 0.125f;
        qo.z = (q4.z + bq4.z) * 0.125f;
        qo.w = (q4.w + bq4.w) * 0.125f;
        ((float4*)qtl)[t] = qo;
    }
    __syncthreads();

    // qk[i] = sum_c Wk2[i][c] * qt[c]  (row i = lane)
    {
        const float4* Wrow = (const float4*)(Wk2 + (long)lane * EE);
        const float4* qt4  = (const float4*)qtl;
        float qa = 0.f, qb = 0.f;
#pragma unroll
        for (int j = 0; j < 16; j += 2) {
            const float4 w0 = Wrow[j],     x0 = qt4[j];
            const float4 w1 = Wrow[j + 1], x1 = qt4[j + 1];
            qa = fmaf(w0.x, x0.x, qa); qb = fmaf(w0.y, x0.y, qb);
            qa = fmaf(w0.z, x0.z, qa); qb = fmaf(w0.w, x0.w, qb);
            qa = fmaf(w1.x, x1.x, qa); qb = fmaf(w1.y, x1.y, qb);
            qa = fmaf(w1.z, x1.z, qa); qb = fmaf(w1.w, x1.w, qb);
        }
        qkl[lane] = qa + qb;
    }
    __syncthreads();

    // scores over res rows (d_out rows 1..128 of batch b)
    const float* Rbase = out + ((long)b * 129 + 1) * EE;
    const float4 qk4 = ((const float4*)qkl)[t];
    float mx = -1e30f;
#pragma unroll 4
    for (int it = 0; it < 32; ++it) {
        const int j = it * 4 + s;
        const float4 r4 = ((const float4*)(Rbase + (long)j * EE))[t];
        float p = qk4.x * r4.x + qk4.y * r4.y + qk4.z * r4.z + qk4.w * r4.w;
        p += __shfl_xor(p, 1); p += __shfl_xor(p, 2);
        p += __shfl_xor(p, 4); p += __shfl_xor(p, 8);
        mx = fmaxf(mx, p);
        if (t == 0) sc[j] = p;
    }
#pragma unroll
    for (int off = 32; off >= 1; off >>= 1) mx = fmaxf(mx, __shfl_xor(mx, off));
    __syncthreads();

    float sum = 0.0f;
#pragma unroll
    for (int j = lane; j < MM; j += 64) {
        const float e = __expf(sc[j] - mx);
        sc[j] = e;
        sum += e;
    }
#pragma unroll
    for (int off = 32; off >= 1; off >>= 1) sum += __shfl_xor(sum, off);
    const float inv = 1.0f / sum;
    __syncthreads();

    // rbar = sum_j p_j res_j
    float4 b4 = make_float4(0.f, 0.f, 0.f, 0.f);
#pragma unroll 4
    for (int it = 0; it < 32; ++it) {
        const int j = it * 4 + s;
        const float w = sc[j];
        const float4 rr = ((const float4*)(Rbase + (long)j * EE))[t];
        b4.x = fmaf(w, rr.x, b4.x); b4.y = fmaf(w, rr.y, b4.y);
        b4.z = fmaf(w, rr.z, b4.z); b4.w = fmaf(w, rr.w, b4.w);
    }
    b4.x += __shfl_xor(b4.x, 16); b4.y += __shfl_xor(b4.y, 16);
    b4.z += __shfl_xor(b4.z, 16); b4.w += __shfl_xor(b4.w, 16);
    b4.x += __shfl_xor(b4.x, 32); b4.y += __shfl_xor(b4.y, 32);
    b4.z += __shfl_xor(b4.z, 32); b4.w += __shfl_xor(b4.w, 32);
    if (s == 0) {
        float4 o; o.x = b4.x * inv; o.y = b4.y * inv; o.z = b4.z * inv; o.w = b4.w * inv;
        ((float4*)av)[t] = o;
    }
    __syncthreads();

    // attnV = rbar @ Wv2 + bv2 -> tmp
    const float4 vv = matvec64(Wv2, av, s, t);
    if (s == 0) {
        const float4 bv4 = ((const float4*)bv2)[t];
        float4 w; w.x = vv.x + bv4.x; w.y = vv.y + bv4.y; w.z = vv.z + bv4.z; w.w = vv.w + bv4.w;
        ((float4*)tmp)[t] = w;
    }
    __syncthreads();

    // row0 = t_a + attnV @ Wo2 + bo2
    const float4 o4 = matvec64(Wo2, tmp, s, t);
    if (s == 0) {
        const float4 bo4 = ((const float4*)bo2)[t];
        float4 r;
        r.x = ta.x + o4.x + bo4.x;
        r.y = ta.y + o4.y + bo4.y;
        r.z = ta.z + o4.z + bo4.z;
        r.w = ta.w + o4.w + bo4.w;
        ((float4*)(out + (long)b * 129 * EE))[t] = r;
    }
}

// ---------------------------------------------------------------------------
extern "C" void kernel_launch(void* const* d_in, const int* in_sizes, int n_in,
                              void* d_out, int out_size, void* d_ws, size_t ws_size,
                              hipStream_t stream)
{
    const float* map_states   = (const float*)d_in[0];
    const float* agent_states = (const float*)d_in[1];
    const float* m_W1 = (const float*)d_in[2];
    const float* m_b1 = (const float*)d_in[3];
    const float* m_g1 = (const float*)d_in[4];
    const float* m_be1 = (const float*)d_in[5];
    const float* m_W2 = (const float*)d_in[6];
    const float* m_b2 = (const float*)d_in[7];
    const float* m_g2 = (const float*)d_in[8];
    const float* m_be2 = (const float*)d_in[9];
    const float* a_W1 = (const float*)d_in[10];
    const float* a_b1 = (const float*)d_in[11];
    const float* a_g1 = (const float*)d_in[12];
    const float* a_be1 = (const float*)d_in[13];
    const float* a_W2 = (const float*)d_in[14];
    const float* a_b2 = (const float*)d_in[15];
    const float* a_g2 = (const float*)d_in[16];
    const float* a_be2 = (const float*)d_in[17];
    const float* att_Wq = (const float*)d_in[18];
    const float* att_bq = (const float*)d_in[19];
    const float* att_Wk = (const float*)d_in[20];
    const float* att_bk = (const float*)d_in[21];
    const float* att_Wv = (const float*)d_in[22];
    const float* att_bv = (const float*)d_in[23];
    const float* att_Wo = (const float*)d_in[24];
    const float* att_bo = (const float*)d_in[25];

    float* out = (float*)d_out;

    // ws layout (floats)
    float* ws      = (float*)d_ws;
    float* map_emb = ws;                          // 32*128*64
    float* target  = map_emb + BB * MM * EE;      // 32*64
    float* Qb      = target + BB * EE;            // 32*128*64
    float* Kb      = Qb + BB * MM * EE;           // 32*129*64
    float* Vb      = Kb + BB * 129 * EE;          // 32*129*64

    const float* Wq0 = att_Wq + 0 * EE * EE; const float* bq0 = att_bq + 0 * EE;
    const float* Wk0 = att_Wk + 0 * EE * EE; const float* bk0 = att_bk + 0 * EE;
    const float* Wv0 = att_Wv + 0 * EE * EE; const float* bv0 = att_bv + 0 * EE;
    const float* Wo0 = att_Wo + 0 * EE * EE; const float* bo0 = att_bo + 0 * EE;
    const float* Wv1 = att_Wv + 1 * EE * EE; const float* bv1 = att_bv + 1 * EE;
    const float* Wo1 = att_Wo + 1 * EE * EE; const float* bo1 = att_bo + 1 * EE;
    const float* Wq2 = att_Wq + 2 * EE * EE; const float* bq2 = att_bq + 2 * EE;
    const float* Wk2 = att_Wk + 2 * EE * EE;
    const float* Wv2 = att_Wv + 2 * EE * EE; const float* bv2 = att_bv + 2 * EE;
    const float* Wo2 = att_Wo + 2 * EE * EE; const float* bo2 = att_bo + 2 * EE;

    // 1. fused local graphs + QKV projections (map: 4096 blocks, agent: 32)
    hipLaunchKernelGGL(lg_qkv_kernel, dim3(BB * MM + BB), dim3(320), 0, stream,
                       map_states, agent_states,
                       m_W1, m_b1, m_g1, m_be1, m_W2, m_b2, m_g2, m_be2,
                       a_W1, a_b1, a_g1, a_be1, a_W2, a_b2, a_g2, a_be2,
                       Wq0, bq0, Wk0, bk0, Wv0, bv0,
                       map_emb, target, Qb, Kb, Vb);

    // 2. a2m attention (online softmax) + residual -> d_out rows 1..128
    hipLaunchKernelGGL(attn_fused_kernel, dim3(BB * MM), dim3(64), 0, stream,
                       map_emb, Qb, Kb, Vb, Wo0, bo0, out);

    // 3. target row (reads res rows from d_out; no K2/V2 needed)
    hipLaunchKernelGGL(target_kernel, dim3(BB), dim3(64), 0, stream,
                       target, Wq2, bq2, Wk2, Wv2, bv2, Wo2, bo2,
                       Wv1, bv1, Wo1, bo1, out);
}